// Round 6
// baseline (2490.682 us; speedup 1.0000x reference)
//
#include <hip/hip_runtime.h>
#include <hip/hip_bf16.h>
#include <math.h>

// Problem constants (from reference)
#define NB   8
#define LSEQ 1024
#define DM   768
#define DI   1536
#define NST  16
#define DTR  48
#define TT   (NB * LSEQ)   // 8192 tokens per input

typedef __attribute__((ext_vector_type(8))) short bf16x8;
typedef __attribute__((ext_vector_type(4))) float f32x4;

__device__ __forceinline__ float silu_f(float x) { return x / (1.f + __expf(-x)); }
__device__ __forceinline__ float softplus_f(float x) { return x > 20.f ? x : log1pf(__expf(x)); }

// ---------------------------------------------------------------------------
// fp32 -> bf16 conversion (n must be a multiple of 4)
// ---------------------------------------------------------------------------
__global__ __launch_bounds__(256) void f2bf_k(
    const float* __restrict__ in, __hip_bfloat16* __restrict__ out, long n4)
{
    const long i = (long)blockIdx.x * 256 + threadIdx.x;
    if (i >= n4) return;
    const float4 v = ((const float4*)in)[i];
    out[i * 4 + 0] = __float2bfloat16(v.x);
    out[i * 4 + 1] = __float2bfloat16(v.y);
    out[i * 4 + 2] = __float2bfloat16(v.z);
    out[i * 4 + 3] = __float2bfloat16(v.w);
}

// ---------------------------------------------------------------------------
// bf16 MFMA GEMM: C[M,N] (fp32) = A[M,K] @ Bw[N,K]^T, A/Bw bf16 row-major,
// K contiguous. 128x128 tile, BK=32, 256 threads = 4 waves (2x2), 4x4
// 16x16x32 fragments per wave. Reg-staged double-buffered LDS with XOR
// swizzle slot^=(row>>1)&3 applied on BOTH write and read sides.
// Requires: M%128==0, N%128==0, K%32==0.
// ---------------------------------------------------------------------------
__global__ __launch_bounds__(256) void gemm_bf16(
    const __hip_bfloat16* __restrict__ A, int lda,
    const __hip_bfloat16* __restrict__ Bw, int ldb,
    float* __restrict__ C, int ldc, int K)
{
    __shared__ short lds[2][8192];      // [buf][ A 128x32 | B 128x32 ] bf16
    const int tid = threadIdx.x;
    const int lane = tid & 63;
    const int wv = tid >> 6;
    const int wm = wv >> 1;             // 0..1
    const int wn = wv & 1;              // 0..1
    const long m0 = (long)blockIdx.y * 128;
    const long n0 = (long)blockIdx.x * 128;

    const int srow = tid >> 2;          // 0..63
    const int skslot = tid & 3;
    const int sswz = skslot ^ ((srow >> 1) & 3);
    const __hip_bfloat16* gA0 = A  + (m0 + srow) * (long)lda + skslot * 8;
    const __hip_bfloat16* gA1 = gA0 + 64l * lda;
    const __hip_bfloat16* gB0 = Bw + (n0 + srow) * (long)ldb + skslot * 8;
    const __hip_bfloat16* gB1 = gB0 + 64l * ldb;
    const int wA0 = srow * 32 + sswz * 8;
    const int wA1 = (srow + 64) * 32 + sswz * 8;
    const int wB0 = 4096 + srow * 32 + sswz * 8;
    const int wB1 = 4096 + (srow + 64) * 32 + sswz * 8;

    const int frow = lane & 15;         // fragment row-in-16
    const int fk = lane >> 4;           // fragment k-slot 0..3

    f32x4 acc[4][4] = {};

    const int NK = K / 32;
    int4 r0, r1, r2, r3;
    r0 = *(const int4*)gA0; r1 = *(const int4*)gA1;
    r2 = *(const int4*)gB0; r3 = *(const int4*)gB1;
    *(int4*)&lds[0][wA0] = r0; *(int4*)&lds[0][wA1] = r1;
    *(int4*)&lds[0][wB0] = r2; *(int4*)&lds[0][wB1] = r3;

    for (int ks = 0; ks < NK; ks++) {
        const int cur = ks & 1;
        if (ks + 1 < NK) {              // issue next tile's global loads early
            const long ko = (long)(ks + 1) * 32;
            r0 = *(const int4*)(gA0 + ko); r1 = *(const int4*)(gA1 + ko);
            r2 = *(const int4*)(gB0 + ko); r3 = *(const int4*)(gB1 + ko);
        }
        __syncthreads();                // staging of `cur` visible to all
        bf16x8 af[4], bfr[4];
        #pragma unroll
        for (int mf = 0; mf < 4; mf++) {
            const int row = wm * 64 + mf * 16 + frow;
            const int sl = fk ^ ((row >> 1) & 3);
            af[mf] = *(const bf16x8*)&lds[cur][row * 32 + sl * 8];
        }
        #pragma unroll
        for (int nf = 0; nf < 4; nf++) {
            const int row = wn * 64 + nf * 16 + frow;
            const int sl = fk ^ ((row >> 1) & 3);
            bfr[nf] = *(const bf16x8*)&lds[cur][4096 + row * 32 + sl * 8];
        }
        #pragma unroll
        for (int mf = 0; mf < 4; mf++)
            #pragma unroll
            for (int nf = 0; nf < 4; nf++)
                acc[mf][nf] = __builtin_amdgcn_mfma_f32_16x16x32_bf16(
                    af[mf], bfr[nf], acc[mf][nf], 0, 0, 0);
        if (ks + 1 < NK) {              // write next tile into other buffer
            const int nb = cur ^ 1;
            *(int4*)&lds[nb][wA0] = r0; *(int4*)&lds[nb][wA1] = r1;
            *(int4*)&lds[nb][wB0] = r2; *(int4*)&lds[nb][wB1] = r3;
        }
    }

    // epilogue: C/D layout col=lane&15, row=(lane>>4)*4+j  [m89-verified]
    #pragma unroll
    for (int mf = 0; mf < 4; mf++) {
        #pragma unroll
        for (int nf = 0; nf < 4; nf++) {
            const long col = n0 + wn * 64 + nf * 16 + (lane & 15);
            const long rw = m0 + wm * 64 + mf * 16 + (lane >> 4) * 4;
            float* cp = C + rw * ldc + col;
            #pragma unroll
            for (int j = 0; j < 4; j++)
                cp[(long)j * ldc] = acc[mf][nf][j];
        }
    }
}

// ---------------------------------------------------------------------------
// Generic fp32 GEMM (kept for x_proj / dt_proj): C = A @ Bw^T
// EPI: 0 = none, 1 = softplus(x + bias[n])
// ---------------------------------------------------------------------------
template <int EPI>
__global__ __launch_bounds__(256) void gemm_nt(
    const float* __restrict__ A, int lda,
    const float* __restrict__ Bw, int ldb,
    float* __restrict__ C, int ldc,
    int M, int N, int K,
    const float* __restrict__ bias)
{
    __shared__ float As[16][68];
    __shared__ float Bs[16][68];
    const int tid = threadIdx.x;
    const int m0 = blockIdx.y * 64;
    const int n0 = blockIdx.x * 64;
    const int tx = tid & 15;
    const int ty = tid >> 4;
    const int lrow = tid >> 2;
    const int lk4 = (tid & 3) << 2;

    float acc[4][4] = {};

    for (int k0 = 0; k0 < K; k0 += 16) {
        float4 av = make_float4(0.f, 0.f, 0.f, 0.f);
        float4 bv = make_float4(0.f, 0.f, 0.f, 0.f);
        const int arow = m0 + lrow;
        if (arow < M)
            av = *reinterpret_cast<const float4*>(A + (long)arow * lda + k0 + lk4);
        const int brow = n0 + lrow;
        if (brow < N)
            bv = *reinterpret_cast<const float4*>(Bw + (long)brow * ldb + k0 + lk4);
        __syncthreads();
        As[lk4 + 0][lrow] = av.x; As[lk4 + 1][lrow] = av.y;
        As[lk4 + 2][lrow] = av.z; As[lk4 + 3][lrow] = av.w;
        Bs[lk4 + 0][lrow] = bv.x; Bs[lk4 + 1][lrow] = bv.y;
        Bs[lk4 + 2][lrow] = bv.z; Bs[lk4 + 3][lrow] = bv.w;
        __syncthreads();
        #pragma unroll
        for (int k = 0; k < 16; k++) {
            float a[4], b[4];
            #pragma unroll
            for (int i = 0; i < 4; i++) a[i] = As[k][ty * 4 + i];
            #pragma unroll
            for (int j = 0; j < 4; j++) b[j] = Bs[k][tx * 4 + j];
            #pragma unroll
            for (int i = 0; i < 4; i++)
                #pragma unroll
                for (int j = 0; j < 4; j++)
                    acc[i][j] = fmaf(a[i], b[j], acc[i][j]);
        }
    }

    #pragma unroll
    for (int i = 0; i < 4; i++) {
        const int m = m0 + ty * 4 + i;
        if (m >= M) continue;
        #pragma unroll
        for (int j = 0; j < 4; j++) {
            const int n = n0 + tx * 4 + j;
            if (n >= N) continue;
            float v = acc[i][j];
            if (EPI == 1) v = softplus_f(v + bias[n]);
            C[(long)m * ldc + n] = v;
        }
    }
}

// ---------------------------------------------------------------------------
// Depthwise causal conv (fwd) + anticausal conv (bwd), + bias + SiLU.
// ---------------------------------------------------------------------------
__global__ __launch_bounds__(256) void conv_silu_k(
    const float* __restrict__ xz,
    const float* __restrict__ cw, const float* __restrict__ cb,
    const float* __restrict__ cwb, const float* __restrict__ cbb,
    float* __restrict__ outf, float* __restrict__ outb, int nt)
{
    const long idx = (long)blockIdx.x * 256 + threadIdx.x;
    if (idx >= (long)nt * DI) return;
    const int d = (int)(idx % DI);
    const long t = idx / DI;
    const int l = (int)(t % LSEQ);
    const float* base = xz + t * (2 * DI) + d;

    float af = cb[d];
    float ab = cbb[d];
    #pragma unroll
    for (int k = 0; k < 4; k++) {
        const int dl = k - 3;
        if (l + dl >= 0) af += cw[d * 4 + k] * base[(long)dl * (2 * DI)];
        const int dl2 = 3 - k;
        if (l + dl2 < LSEQ) ab += cwb[d * 4 + k] * base[(long)dl2 * (2 * DI)];
    }
    outf[idx] = silu_f(af);
    outb[idx] = silu_f(ab);
}

// ---------------------------------------------------------------------------
// Selective scan, both directions (blockIdx.z = dir).
// Layout: 4 threads per channel (sub = tid&3), 4 states per thread; a
// 256-thread block covers 64 consecutive channels of one sequence.
// B/C (shared by all channels) are staged per 8-step tile into a 2KB
// double-buffered LDS stage (saves 128 VGPRs of redundant per-thread
// copies vs register tiles -> no spill). u/dt stay in 8-step register
// tiles. One __syncthreads per tile. y overwrites the dt buffer in place
// (loads for tile k+2 precede stores of tile k+1 in program order;
// disjoint token indices).
// ---------------------------------------------------------------------------
#define TS 8
#define NTILE (LSEQ / TS)

__global__ __launch_bounds__(256) void scan_k(
    const float* __restrict__ uf, float* __restrict__ yf, const float* __restrict__ dblf,
    const float* __restrict__ Alf, const float* __restrict__ Df,
    const float* __restrict__ ub, float* __restrict__ yb, const float* __restrict__ dblb,
    const float* __restrict__ Alb, const float* __restrict__ Db)
{
    const int dir = blockIdx.z;
    const float* u_   = dir ? ub   : uf;
    float*       y_   = dir ? yb   : yf;
    const float* dbl_ = dir ? dblb : dblf;
    const float* Al   = dir ? Alb  : Alf;
    const float* Dp   = dir ? Db   : Df;

    const int tid = threadIdx.x;
    const int sub = tid & 3;            // state group 0..3 (states sub*4..sub*4+3)
    const int chl = tid >> 2;           // channel-in-block 0..63
    const int d = blockIdx.x * 64 + chl;
    const int b = blockIdx.y;

    __shared__ float bc[2][TS][32];     // [buf][token-in-tile][B(16)|C(16)]
    const int sit = tid >> 5;           // staging token-in-tile 0..7
    const int sje = tid & 31;           // staging element 0..31

    const float An0 = -__expf(Al[d * NST + sub * 4 + 0]);
    const float An1 = -__expf(Al[d * NST + sub * 4 + 1]);
    const float An2 = -__expf(Al[d * NST + sub * 4 + 2]);
    const float An3 = -__expf(Al[d * NST + sub * 4 + 3]);
    const float Dd = Dp[d];
    float h0 = 0.f, h1 = 0.f, h2 = 0.f, h3 = 0.f;
    const long tbase = (long)b * LSEQ;
    const int stp = dir ? -1 : 1;
    const int l0  = dir ? (LSEQ - 1) : 0;

#define STAGE(buf, tile)                                                \
    {                                                                   \
        const int l = l0 + ((tile) * TS + sit) * stp;                   \
        bc[buf][sit][sje] = dbl_[(tbase + l) * 80 + DTR + sje];         \
    }

#define LOADUD(U, DT, tile)                                             \
    {                                                                   \
        _Pragma("unroll")                                               \
        for (int i = 0; i < TS; i++) {                                  \
            const long t = tbase + l0 + ((tile) * TS + i) * stp;        \
            U[i]  = u_[t * DI + d];                                     \
            DT[i] = y_[t * DI + d];                                     \
        }                                                               \
    }

#define COMPT(U, DT, buf, tile)                                         \
    {                                                                   \
        _Pragma("unroll")                                               \
        for (int i = 0; i < TS; i++) {                                  \
            const float4 BV = *(const float4*)&bc[buf][i][sub * 4];     \
            const float4 CV = *(const float4*)&bc[buf][i][16 + sub * 4];\
            const float dtu = DT[i] * U[i];                             \
            h0 = h0 * __expf(DT[i] * An0) + dtu * BV.x;                 \
            h1 = h1 * __expf(DT[i] * An1) + dtu * BV.y;                 \
            h2 = h2 * __expf(DT[i] * An2) + dtu * BV.z;                 \
            h3 = h3 * __expf(DT[i] * An3) + dtu * BV.w;                 \
            float p = h0 * CV.x + h1 * CV.y + h2 * CV.z + h3 * CV.w;    \
            p += __shfl_xor(p, 1, 4);                                   \
            p += __shfl_xor(p, 2, 4);                                   \
            if (sub == 0) {                                             \
                const int l = l0 + ((tile) * TS + i) * stp;             \
                y_[(tbase + l) * DI + d] = p + U[i] * Dd;               \
            }                                                           \
        }                                                               \
    }

    float uA[TS], dA_[TS];
    float uB[TS], dB_[TS];

    LOADUD(uA, dA_, 0);
    STAGE(0, 0);
    __syncthreads();
    for (int t2 = 0; t2 < NTILE; t2 += 2) {
        if (t2 + 1 < NTILE) { LOADUD(uB, dB_, t2 + 1); STAGE(1, t2 + 1); }
        COMPT(uA, dA_, 0, t2);
        __syncthreads();    // bc[1] staged; everyone done reading bc[0]
        if (t2 + 2 < NTILE) { LOADUD(uA, dA_, t2 + 2); STAGE(0, t2 + 2); }
        COMPT(uB, dB_, 1, t2 + 1);
        __syncthreads();    // bc[0] staged; everyone done reading bc[1]
    }
#undef STAGE
#undef LOADUD
#undef COMPT
}

// ---------------------------------------------------------------------------
// Gate: g = (yf + yb) * silu(z) -> bf16 (feeds out_proj MFMA GEMM)
// ---------------------------------------------------------------------------
__global__ __launch_bounds__(256) void gate_k(
    const float* __restrict__ yf, const float* __restrict__ yb,
    const float* __restrict__ xz, __hip_bfloat16* __restrict__ g, int nt)
{
    const long idx = (long)blockIdx.x * 256 + threadIdx.x;
    if (idx >= (long)nt * DI) return;
    const int d = (int)(idx % DI);
    const long t = idx / DI;
    const float z = xz[t * (2 * DI) + DI + d];
    g[idx] = __float2bfloat16((yf[idx] + yb[idx]) * silu_f(z));
}

// ---------------------------------------------------------------------------
// out = xin + rmsnorm(mo, w);  one block per token
// ---------------------------------------------------------------------------
__global__ __launch_bounds__(256) void rmsnorm_res_k(
    const float* __restrict__ mo, const float* __restrict__ xin,
    const float* __restrict__ w, float* __restrict__ out)
{
    const int t = blockIdx.x;
    const int tid = threadIdx.x;
    const long base = (long)t * DM;
    const float v0 = mo[base + tid];
    const float v1 = mo[base + tid + 256];
    const float v2 = mo[base + tid + 512];
    float ss = v0 * v0 + v1 * v1 + v2 * v2;
    #pragma unroll
    for (int m = 1; m < 64; m <<= 1) ss += __shfl_xor(ss, m, 64);
    __shared__ float red[4];
    if ((tid & 63) == 0) red[tid >> 6] = ss;
    __syncthreads();
    const float tot = red[0] + red[1] + red[2] + red[3];
    const float sc = rsqrtf(tot * (1.f / DM) + 1e-5f);
    out[base + tid]       = xin[base + tid]       + v0 * sc * w[tid];
    out[base + tid + 256] = xin[base + tid + 256] + v1 * sc * w[tid + 256];
    out[base + tid + 512] = xin[base + tid + 512] + v2 * sc * w[tid + 512];
}

// ---------------------------------------------------------------------------
extern "C" void kernel_launch(void* const* d_in, const int* in_sizes, int n_in,
                              void* d_out, int out_size, void* d_ws, size_t ws_size,
                              hipStream_t stream)
{
    const float* m_x         = (const float*)d_in[0];
    const float* n_x         = (const float*)d_in[1];
    const float* in_proj_w   = (const float*)d_in[2];
    const float* conv_w      = (const float*)d_in[3];
    const float* conv_b      = (const float*)d_in[4];
    const float* x_proj_w    = (const float*)d_in[5];
    const float* dt_proj_w   = (const float*)d_in[6];
    const float* dt_proj_b   = (const float*)d_in[7];
    const float* A_log       = (const float*)d_in[8];
    const float* Dp          = (const float*)d_in[9];
    const float* conv_w_b    = (const float*)d_in[10];
    const float* conv_b_b    = (const float*)d_in[11];
    const float* x_proj_w_b  = (const float*)d_in[12];
    const float* dt_proj_w_b = (const float*)d_in[13];
    const float* dt_proj_b_b = (const float*)d_in[14];
    const float* A_log_b     = (const float*)d_in[15];
    const float* D_b         = (const float*)d_in[16];
    const float* out_proj_w  = (const float*)d_in[17];
    const float* norm1_w     = (const float*)d_in[18];
    const float* norm2_w     = (const float*)d_in[19];

    // ---- workspace layout: fixed bf16 weight copies first, then per-chunk
    const long W_IN  = (long)(2 * DI) * DM;   // 2,359,296 elements
    const long W_OUT = (long)DM * DI;         // 1,179,648 elements
    char* wsc = (char*)d_ws;
    __hip_bfloat16* wbf_in  = (__hip_bfloat16*)wsc;
    __hip_bfloat16* wbf_out = wbf_in + W_IN;
    char* chunk_base = (char*)(wbf_out + W_OUT);
    const size_t fixed_bytes = (size_t)(W_IN + W_OUT) * 2;

    // per-batch floats: xz 3072 + convf/b 2*1536 + dblf/b 2*80 + dtf/b 2*1536
    //                 + abf (1536 bf16 = 768 f32-equiv)   per token
    const long PBF = (long)LSEQ * (3072 + 2 * 1536 + 2 * 80 + 2 * 1536 + 768);
    int CB = (int)((ws_size - fixed_bytes) / ((size_t)PBF * 4));
    if (CB < 1) CB = 1;
    if (CB > NB) CB = NB;

    const long CT = (long)CB * LSEQ;
    float* fb    = (float*)chunk_base;
    float* xz    = fb;                       // CT * 3072
    float* convf = xz    + CT * 2 * DI;      // CT * 1536
    float* convb = convf + CT * DI;          // CT * 1536
    float* dblf  = convb + CT * DI;          // CT * 80
    float* dblb  = dblf  + CT * 80;          // CT * 80
    float* dtf   = dblb  + CT * 80;          // CT * 1536 (scan -> yf in place)
    float* dtb   = dtf   + CT * DI;          // CT * 1536 (scan -> yb in place)
    __hip_bfloat16* abf = (__hip_bfloat16*)(dtb + CT * DI);  // CT * 1536 bf16

    const dim3 blk(256);

    // convert projection weights to bf16 once
    f2bf_k<<<dim3((W_IN / 4 + 255) / 256), blk, 0, stream>>>(in_proj_w, wbf_in, W_IN / 4);
    f2bf_k<<<dim3((W_OUT / 4 + 255) / 256), blk, 0, stream>>>(out_proj_w, wbf_out, W_OUT / 4);

    for (int which = 0; which < 2; which++) {
        const float* xin0 = which ? n_x : m_x;
        const float* nw   = which ? norm2_w : norm1_w;
        float* out0 = (float*)d_out + (long)which * TT * DM;

        for (int b0 = 0; b0 < NB; b0 += CB) {
            const int cb = (NB - b0) < CB ? (NB - b0) : CB;
            const int nt = cb * LSEQ;
            const float* xin = xin0 + (long)b0 * LSEQ * DM;
            float* outp = out0 + (long)b0 * LSEQ * DM;

            // A -> bf16, then in_proj via MFMA:
            // xz[nt,3072] = xin_bf[nt,768] @ wbf_in[3072,768]^T
            f2bf_k<<<dim3(((long)nt * DM / 4 + 255) / 256), blk, 0, stream>>>(
                xin, abf, (long)nt * DM / 4);
            gemm_bf16<<<dim3((2 * DI) / 128, nt / 128), blk, 0, stream>>>(
                abf, DM, wbf_in, DM, xz, 2 * DI, DM);

            // depthwise conv + silu, both directions
            conv_silu_k<<<dim3(((long)nt * DI + 255) / 256), blk, 0, stream>>>(
                xz, conv_w, conv_b, conv_w_b, conv_b_b, convf, convb, nt);

            // x_proj (fp32): dbl[nt,80] = conv @ x_proj_w[80,1536]^T
            gemm_nt<0><<<dim3(2, nt / 64), blk, 0, stream>>>(
                convf, DI, x_proj_w, DI, dblf, 80, nt, 80, DI, nullptr);
            gemm_nt<0><<<dim3(2, nt / 64), blk, 0, stream>>>(
                convb, DI, x_proj_w_b, DI, dblb, 80, nt, 80, DI, nullptr);

            // dt_proj (fp32): dt[nt,1536] = softplus(dbl[:, :48] @ w^T + b)
            gemm_nt<1><<<dim3(DI / 64, nt / 64), blk, 0, stream>>>(
                dblf, 80, dt_proj_w, DTR, dtf, DI, nt, DI, DTR, dt_proj_b);
            gemm_nt<1><<<dim3(DI / 64, nt / 64), blk, 0, stream>>>(
                dblb, 80, dt_proj_w_b, DTR, dtb, DI, nt, DI, DTR, dt_proj_b_b);

            // selective scan, fwd + bwd (y overwrites dt buffers)
            scan_k<<<dim3(DI / 64, cb, 2), blk, 0, stream>>>(
                convf, dtf, dblf, A_log, Dp,
                convb, dtb, dblb, A_log_b, D_b);

            // gate -> bf16 A operand for out_proj
            gate_k<<<dim3(((long)nt * DI + 255) / 256), blk, 0, stream>>>(
                dtf, dtb, xz, abf, nt);

            // out_proj via MFMA: mo[nt,768] = g_bf @ wbf_out[768,1536]^T
            gemm_bf16<<<dim3(DM / 128, nt / 128), blk, 0, stream>>>(
                abf, DI, wbf_out, DI, convb, DM, DI);

            // residual + rmsnorm
            rmsnorm_res_k<<<dim3(nt), blk, 0, stream>>>(convb, xin, nw, outp);
        }
    }
}

// Round 7
// 2460.825 us; speedup vs baseline: 1.0121x; 1.0121x over previous
//
#include <hip/hip_runtime.h>
#include <hip/hip_bf16.h>
#include <math.h>

// Problem constants (from reference)
#define NB   8
#define LSEQ 1024
#define DM   768
#define DI   1536
#define NST  16
#define DTR  48
#define TT   (NB * LSEQ)   // 8192 tokens per input

typedef __attribute__((ext_vector_type(8))) short bf16x8;
typedef __attribute__((ext_vector_type(4))) float f32x4;

__device__ __forceinline__ float silu_f(float x) { return x / (1.f + __expf(-x)); }
__device__ __forceinline__ float softplus_f(float x) { return x > 20.f ? x : log1pf(__expf(x)); }

// 4-lane XOR-add via DPP quad_perm (pure VALU — no LDS pipe).
// 0xB1 = quad_perm[1,0,3,2] (xor 1), 0x4E = quad_perm[2,3,0,1] (xor 2).
template <int CTRL>
__device__ __forceinline__ float dpp_xor_add(float x) {
    int yi = __builtin_amdgcn_update_dpp(0, __float_as_int(x), CTRL, 0xF, 0xF, true);
    return x + __int_as_float(yi);
}

// ---------------------------------------------------------------------------
// fp32 -> bf16 conversion (n must be a multiple of 4)
// ---------------------------------------------------------------------------
__global__ __launch_bounds__(256) void f2bf_k(
    const float* __restrict__ in, __hip_bfloat16* __restrict__ out, long n4)
{
    const long i = (long)blockIdx.x * 256 + threadIdx.x;
    if (i >= n4) return;
    const float4 v = ((const float4*)in)[i];
    out[i * 4 + 0] = __float2bfloat16(v.x);
    out[i * 4 + 1] = __float2bfloat16(v.y);
    out[i * 4 + 2] = __float2bfloat16(v.z);
    out[i * 4 + 3] = __float2bfloat16(v.w);
}

// ---------------------------------------------------------------------------
// bf16 MFMA GEMM: C[M,N] (fp32) = A[M,K] @ Bw[N,K]^T, A/Bw bf16 row-major,
// K contiguous. 128x128 tile, BK=32, 256 threads = 4 waves (2x2), 4x4
// 16x16x32 fragments per wave. Reg-staged double-buffered LDS with XOR
// swizzle slot^=(row>>1)&3 applied on BOTH write and read sides.
// Requires: M%128==0, N%128==0, K%32==0.
// ---------------------------------------------------------------------------
__global__ __launch_bounds__(256) void gemm_bf16(
    const __hip_bfloat16* __restrict__ A, int lda,
    const __hip_bfloat16* __restrict__ Bw, int ldb,
    float* __restrict__ C, int ldc, int K)
{
    __shared__ short lds[2][8192];      // [buf][ A 128x32 | B 128x32 ] bf16
    const int tid = threadIdx.x;
    const int lane = tid & 63;
    const int wv = tid >> 6;
    const int wm = wv >> 1;             // 0..1
    const int wn = wv & 1;              // 0..1
    const long m0 = (long)blockIdx.y * 128;
    const long n0 = (long)blockIdx.x * 128;

    const int srow = tid >> 2;          // 0..63
    const int skslot = tid & 3;
    const int sswz = skslot ^ ((srow >> 1) & 3);
    const __hip_bfloat16* gA0 = A  + (m0 + srow) * (long)lda + skslot * 8;
    const __hip_bfloat16* gA1 = gA0 + 64l * lda;
    const __hip_bfloat16* gB0 = Bw + (n0 + srow) * (long)ldb + skslot * 8;
    const __hip_bfloat16* gB1 = gB0 + 64l * ldb;
    const int wA0 = srow * 32 + sswz * 8;
    const int wA1 = (srow + 64) * 32 + sswz * 8;
    const int wB0 = 4096 + srow * 32 + sswz * 8;
    const int wB1 = 4096 + (srow + 64) * 32 + sswz * 8;

    const int frow = lane & 15;         // fragment row-in-16
    const int fk = lane >> 4;           // fragment k-slot 0..3

    f32x4 acc[4][4] = {};

    const int NK = K / 32;
    int4 r0, r1, r2, r3;
    r0 = *(const int4*)gA0; r1 = *(const int4*)gA1;
    r2 = *(const int4*)gB0; r3 = *(const int4*)gB1;
    *(int4*)&lds[0][wA0] = r0; *(int4*)&lds[0][wA1] = r1;
    *(int4*)&lds[0][wB0] = r2; *(int4*)&lds[0][wB1] = r3;

    for (int ks = 0; ks < NK; ks++) {
        const int cur = ks & 1;
        if (ks + 1 < NK) {              // issue next tile's global loads early
            const long ko = (long)(ks + 1) * 32;
            r0 = *(const int4*)(gA0 + ko); r1 = *(const int4*)(gA1 + ko);
            r2 = *(const int4*)(gB0 + ko); r3 = *(const int4*)(gB1 + ko);
        }
        __syncthreads();                // staging of `cur` visible to all
        bf16x8 af[4], bfr[4];
        #pragma unroll
        for (int mf = 0; mf < 4; mf++) {
            const int row = wm * 64 + mf * 16 + frow;
            const int sl = fk ^ ((row >> 1) & 3);
            af[mf] = *(const bf16x8*)&lds[cur][row * 32 + sl * 8];
        }
        #pragma unroll
        for (int nf = 0; nf < 4; nf++) {
            const int row = wn * 64 + nf * 16 + frow;
            const int sl = fk ^ ((row >> 1) & 3);
            bfr[nf] = *(const bf16x8*)&lds[cur][4096 + row * 32 + sl * 8];
        }
        #pragma unroll
        for (int mf = 0; mf < 4; mf++)
            #pragma unroll
            for (int nf = 0; nf < 4; nf++)
                acc[mf][nf] = __builtin_amdgcn_mfma_f32_16x16x32_bf16(
                    af[mf], bfr[nf], acc[mf][nf], 0, 0, 0);
        if (ks + 1 < NK) {              // write next tile into other buffer
            const int nb = cur ^ 1;
            *(int4*)&lds[nb][wA0] = r0; *(int4*)&lds[nb][wA1] = r1;
            *(int4*)&lds[nb][wB0] = r2; *(int4*)&lds[nb][wB1] = r3;
        }
    }

    // epilogue: C/D layout col=lane&15, row=(lane>>4)*4+j  [m89-verified]
    #pragma unroll
    for (int mf = 0; mf < 4; mf++) {
        #pragma unroll
        for (int nf = 0; nf < 4; nf++) {
            const long col = n0 + wn * 64 + nf * 16 + (lane & 15);
            const long rw = m0 + wm * 64 + mf * 16 + (lane >> 4) * 4;
            float* cp = C + rw * ldc + col;
            #pragma unroll
            for (int j = 0; j < 4; j++)
                cp[(long)j * ldc] = acc[mf][nf][j];
        }
    }
}

// ---------------------------------------------------------------------------
// Generic fp32 GEMM (kept for x_proj / dt_proj): C = A @ Bw^T
// EPI: 0 = none, 1 = softplus(x + bias[n])
// ---------------------------------------------------------------------------
template <int EPI>
__global__ __launch_bounds__(256) void gemm_nt(
    const float* __restrict__ A, int lda,
    const float* __restrict__ Bw, int ldb,
    float* __restrict__ C, int ldc,
    int M, int N, int K,
    const float* __restrict__ bias)
{
    __shared__ float As[16][68];
    __shared__ float Bs[16][68];
    const int tid = threadIdx.x;
    const int m0 = blockIdx.y * 64;
    const int n0 = blockIdx.x * 64;
    const int tx = tid & 15;
    const int ty = tid >> 4;
    const int lrow = tid >> 2;
    const int lk4 = (tid & 3) << 2;

    float acc[4][4] = {};

    for (int k0 = 0; k0 < K; k0 += 16) {
        float4 av = make_float4(0.f, 0.f, 0.f, 0.f);
        float4 bv = make_float4(0.f, 0.f, 0.f, 0.f);
        const int arow = m0 + lrow;
        if (arow < M)
            av = *reinterpret_cast<const float4*>(A + (long)arow * lda + k0 + lk4);
        const int brow = n0 + lrow;
        if (brow < N)
            bv = *reinterpret_cast<const float4*>(Bw + (long)brow * ldb + k0 + lk4);
        __syncthreads();
        As[lk4 + 0][lrow] = av.x; As[lk4 + 1][lrow] = av.y;
        As[lk4 + 2][lrow] = av.z; As[lk4 + 3][lrow] = av.w;
        Bs[lk4 + 0][lrow] = bv.x; Bs[lk4 + 1][lrow] = bv.y;
        Bs[lk4 + 2][lrow] = bv.z; Bs[lk4 + 3][lrow] = bv.w;
        __syncthreads();
        #pragma unroll
        for (int k = 0; k < 16; k++) {
            float a[4], b[4];
            #pragma unroll
            for (int i = 0; i < 4; i++) a[i] = As[k][ty * 4 + i];
            #pragma unroll
            for (int j = 0; j < 4; j++) b[j] = Bs[k][tx * 4 + j];
            #pragma unroll
            for (int i = 0; i < 4; i++)
                #pragma unroll
                for (int j = 0; j < 4; j++)
                    acc[i][j] = fmaf(a[i], b[j], acc[i][j]);
        }
    }

    #pragma unroll
    for (int i = 0; i < 4; i++) {
        const int m = m0 + ty * 4 + i;
        if (m >= M) continue;
        #pragma unroll
        for (int j = 0; j < 4; j++) {
            const int n = n0 + tx * 4 + j;
            if (n >= N) continue;
            float v = acc[i][j];
            if (EPI == 1) v = softplus_f(v + bias[n]);
            C[(long)m * ldc + n] = v;
        }
    }
}

// ---------------------------------------------------------------------------
// Depthwise causal conv (fwd) + anticausal conv (bwd), + bias + SiLU.
// ---------------------------------------------------------------------------
__global__ __launch_bounds__(256) void conv_silu_k(
    const float* __restrict__ xz,
    const float* __restrict__ cw, const float* __restrict__ cb,
    const float* __restrict__ cwb, const float* __restrict__ cbb,
    float* __restrict__ outf, float* __restrict__ outb, int nt)
{
    const long idx = (long)blockIdx.x * 256 + threadIdx.x;
    if (idx >= (long)nt * DI) return;
    const int d = (int)(idx % DI);
    const long t = idx / DI;
    const int l = (int)(t % LSEQ);
    const float* base = xz + t * (2 * DI) + d;

    float af = cb[d];
    float ab = cbb[d];
    #pragma unroll
    for (int k = 0; k < 4; k++) {
        const int dl = k - 3;
        if (l + dl >= 0) af += cw[d * 4 + k] * base[(long)dl * (2 * DI)];
        const int dl2 = 3 - k;
        if (l + dl2 < LSEQ) ab += cwb[d * 4 + k] * base[(long)dl2 * (2 * DI)];
    }
    outf[idx] = silu_f(af);
    outb[idx] = silu_f(ab);
}

// ---------------------------------------------------------------------------
// Selective scan, both directions (blockIdx.z = dir).
// ONE WAVE per block: 16 channels x 4 state-lanes (sub = tid&3). Grid covers
// DI/16 x cb x 2, so all 256 CUs get work. No __syncthreads (single wave;
// LDS RAW ordered by compiler lgkmcnt). B/C staged per 16-step tile into a
// 4KB double-buffered LDS stage; u/dt in 16-step register tiles (double-
// buffered, compile-time indices). 4-lane reduce via DPP quad_perm (pure
// VALU). y overwrites the dt buffer in place (tile k+1 loads are issued
// before tile k's stores only for disjoint token indices).
// ---------------------------------------------------------------------------
#define TS 16
#define NTILE (LSEQ / TS)   // 64

__global__ __launch_bounds__(64) void scan_k(
    const float* __restrict__ uf, float* __restrict__ yf, const float* __restrict__ dblf,
    const float* __restrict__ Alf, const float* __restrict__ Df,
    const float* __restrict__ ub, float* __restrict__ yb, const float* __restrict__ dblb,
    const float* __restrict__ Alb, const float* __restrict__ Db)
{
    const int dir = blockIdx.z;
    const float* u_   = dir ? ub   : uf;
    float*       y_   = dir ? yb   : yf;
    const float* dbl_ = dir ? dblb : dblf;
    const float* Al   = dir ? Alb  : Alf;
    const float* Dp   = dir ? Db   : Df;

    const int tid = threadIdx.x;        // 0..63, one wave
    const int sub = tid & 3;            // state group (states sub*4..sub*4+3)
    const int chl = tid >> 2;           // channel-in-block 0..15
    const int d = blockIdx.x * 16 + chl;
    const int b = blockIdx.y;

    __shared__ float bc[2][TS][32];     // [buf][token-in-tile][B(16)|C(16)]

    const float An0 = -__expf(Al[d * NST + sub * 4 + 0]);
    const float An1 = -__expf(Al[d * NST + sub * 4 + 1]);
    const float An2 = -__expf(Al[d * NST + sub * 4 + 2]);
    const float An3 = -__expf(Al[d * NST + sub * 4 + 3]);
    const float Dd = Dp[d];
    float h0 = 0.f, h1 = 0.f, h2 = 0.f, h3 = 0.f;
    const long tbase = (long)b * LSEQ;
    const int stp = dir ? -1 : 1;
    const int l0  = dir ? (LSEQ - 1) : 0;

    // stage: 16 tokens x 32 floats = 512 elems, 8 per lane
#define STAGE(buf, tile)                                                \
    {                                                                   \
        _Pragma("unroll")                                               \
        for (int r = 0; r < 8; r++) {                                   \
            const int e = r * 64 + tid;                                 \
            const int tok = e >> 5;                                     \
            const int j = e & 31;                                       \
            const int l = l0 + ((tile) * TS + tok) * stp;               \
            bc[buf][tok][j] = dbl_[(tbase + l) * 80 + DTR + j];         \
        }                                                               \
    }

#define LOADUD(U, DT, tile)                                             \
    {                                                                   \
        _Pragma("unroll")                                               \
        for (int i = 0; i < TS; i++) {                                  \
            const long t = tbase + l0 + ((tile) * TS + i) * stp;        \
            U[i]  = u_[t * DI + d];                                     \
            DT[i] = y_[t * DI + d];                                     \
        }                                                               \
    }

#define COMPT(U, DT, buf, tile)                                         \
    {                                                                   \
        _Pragma("unroll")                                               \
        for (int i = 0; i < TS; i++) {                                  \
            const float4 BV = *(const float4*)&bc[buf][i][sub * 4];     \
            const float4 CV = *(const float4*)&bc[buf][i][16 + sub * 4];\
            const float dtu = DT[i] * U[i];                             \
            h0 = h0 * __expf(DT[i] * An0) + dtu * BV.x;                 \
            h1 = h1 * __expf(DT[i] * An1) + dtu * BV.y;                 \
            h2 = h2 * __expf(DT[i] * An2) + dtu * BV.z;                 \
            h3 = h3 * __expf(DT[i] * An3) + dtu * BV.w;                 \
            float p = h0 * CV.x + h1 * CV.y + h2 * CV.z + h3 * CV.w;    \
            p = dpp_xor_add<0xB1>(p);                                   \
            p = dpp_xor_add<0x4E>(p);                                   \
            if (sub == 0) {                                             \
                const int l = l0 + ((tile) * TS + i) * stp;             \
                y_[(tbase + l) * DI + d] = p + U[i] * Dd;               \
            }                                                           \
        }                                                               \
    }

    float uA[TS], dA_[TS];
    float uB[TS], dB_[TS];

    LOADUD(uA, dA_, 0);
    STAGE(0, 0);
    for (int t2 = 0; t2 < NTILE; t2 += 2) {
        if (t2 + 1 < NTILE) { LOADUD(uB, dB_, t2 + 1); STAGE(1, t2 + 1); }
        COMPT(uA, dA_, 0, t2);
        if (t2 + 2 < NTILE) { LOADUD(uA, dA_, t2 + 2); STAGE(0, t2 + 2); }
        COMPT(uB, dB_, 1, t2 + 1);      // NTILE even: t2+1 always valid
    }
#undef STAGE
#undef LOADUD
#undef COMPT
}

// ---------------------------------------------------------------------------
// Gate: g = (yf + yb) * silu(z) -> bf16 (feeds out_proj MFMA GEMM)
// ---------------------------------------------------------------------------
__global__ __launch_bounds__(256) void gate_k(
    const float* __restrict__ yf, const float* __restrict__ yb,
    const float* __restrict__ xz, __hip_bfloat16* __restrict__ g, int nt)
{
    const long idx = (long)blockIdx.x * 256 + threadIdx.x;
    if (idx >= (long)nt * DI) return;
    const int d = (int)(idx % DI);
    const long t = idx / DI;
    const float z = xz[t * (2 * DI) + DI + d];
    g[idx] = __float2bfloat16((yf[idx] + yb[idx]) * silu_f(z));
}

// ---------------------------------------------------------------------------
// out = xin + rmsnorm(mo, w);  one block per token
// ---------------------------------------------------------------------------
__global__ __launch_bounds__(256) void rmsnorm_res_k(
    const float* __restrict__ mo, const float* __restrict__ xin,
    const float* __restrict__ w, float* __restrict__ out)
{
    const int t = blockIdx.x;
    const int tid = threadIdx.x;
    const long base = (long)t * DM;
    const float v0 = mo[base + tid];
    const float v1 = mo[base + tid + 256];
    const float v2 = mo[base + tid + 512];
    float ss = v0 * v0 + v1 * v1 + v2 * v2;
    #pragma unroll
    for (int m = 1; m < 64; m <<= 1) ss += __shfl_xor(ss, m, 64);
    __shared__ float red[4];
    if ((tid & 63) == 0) red[tid >> 6] = ss;
    __syncthreads();
    const float tot = red[0] + red[1] + red[2] + red[3];
    const float sc = rsqrtf(tot * (1.f / DM) + 1e-5f);
    out[base + tid]       = xin[base + tid]       + v0 * sc * w[tid];
    out[base + tid + 256] = xin[base + tid + 256] + v1 * sc * w[tid + 256];
    out[base + tid + 512] = xin[base + tid + 512] + v2 * sc * w[tid + 512];
}

// ---------------------------------------------------------------------------
extern "C" void kernel_launch(void* const* d_in, const int* in_sizes, int n_in,
                              void* d_out, int out_size, void* d_ws, size_t ws_size,
                              hipStream_t stream)
{
    const float* m_x         = (const float*)d_in[0];
    const float* n_x         = (const float*)d_in[1];
    const float* in_proj_w   = (const float*)d_in[2];
    const float* conv_w      = (const float*)d_in[3];
    const float* conv_b      = (const float*)d_in[4];
    const float* x_proj_w    = (const float*)d_in[5];
    const float* dt_proj_w   = (const float*)d_in[6];
    const float* dt_proj_b   = (const float*)d_in[7];
    const float* A_log       = (const float*)d_in[8];
    const float* Dp          = (const float*)d_in[9];
    const float* conv_w_b    = (const float*)d_in[10];
    const float* conv_b_b    = (const float*)d_in[11];
    const float* x_proj_w_b  = (const float*)d_in[12];
    const float* dt_proj_w_b = (const float*)d_in[13];
    const float* dt_proj_b_b = (const float*)d_in[14];
    const float* A_log_b     = (const float*)d_in[15];
    const float* D_b         = (const float*)d_in[16];
    const float* out_proj_w  = (const float*)d_in[17];
    const float* norm1_w     = (const float*)d_in[18];
    const float* norm2_w     = (const float*)d_in[19];

    // ---- workspace layout: fixed bf16 weight copies first, then per-chunk
    const long W_IN  = (long)(2 * DI) * DM;   // 2,359,296 elements
    const long W_OUT = (long)DM * DI;         // 1,179,648 elements
    char* wsc = (char*)d_ws;
    __hip_bfloat16* wbf_in  = (__hip_bfloat16*)wsc;
    __hip_bfloat16* wbf_out = wbf_in + W_IN;
    char* chunk_base = (char*)(wbf_out + W_OUT);
    const size_t fixed_bytes = (size_t)(W_IN + W_OUT) * 2;

    // per-batch floats: xz 3072 + convf/b 2*1536 + dblf/b 2*80 + dtf/b 2*1536
    //                 + abf (1536 bf16 = 768 f32-equiv)   per token
    const long PBF = (long)LSEQ * (3072 + 2 * 1536 + 2 * 80 + 2 * 1536 + 768);
    int CB = (int)((ws_size - fixed_bytes) / ((size_t)PBF * 4));
    if (CB < 1) CB = 1;
    if (CB > NB) CB = NB;

    const long CT = (long)CB * LSEQ;
    float* fb    = (float*)chunk_base;
    float* xz    = fb;                       // CT * 3072
    float* convf = xz    + CT * 2 * DI;      // CT * 1536
    float* convb = convf + CT * DI;          // CT * 1536
    float* dblf  = convb + CT * DI;          // CT * 80
    float* dblb  = dblf  + CT * 80;          // CT * 80
    float* dtf   = dblb  + CT * 80;          // CT * 1536 (scan -> yf in place)
    float* dtb   = dtf   + CT * DI;          // CT * 1536 (scan -> yb in place)
    __hip_bfloat16* abf = (__hip_bfloat16*)(dtb + CT * DI);  // CT * 1536 bf16

    const dim3 blk(256);

    // convert projection weights to bf16 once
    f2bf_k<<<dim3((W_IN / 4 + 255) / 256), blk, 0, stream>>>(in_proj_w, wbf_in, W_IN / 4);
    f2bf_k<<<dim3((W_OUT / 4 + 255) / 256), blk, 0, stream>>>(out_proj_w, wbf_out, W_OUT / 4);

    for (int which = 0; which < 2; which++) {
        const float* xin0 = which ? n_x : m_x;
        const float* nw   = which ? norm2_w : norm1_w;
        float* out0 = (float*)d_out + (long)which * TT * DM;

        for (int b0 = 0; b0 < NB; b0 += CB) {
            const int cb = (NB - b0) < CB ? (NB - b0) : CB;
            const int nt = cb * LSEQ;
            const float* xin = xin0 + (long)b0 * LSEQ * DM;
            float* outp = out0 + (long)b0 * LSEQ * DM;

            // A -> bf16, then in_proj via MFMA:
            // xz[nt,3072] = xin_bf[nt,768] @ wbf_in[3072,768]^T
            f2bf_k<<<dim3(((long)nt * DM / 4 + 255) / 256), blk, 0, stream>>>(
                xin, abf, (long)nt * DM / 4);
            gemm_bf16<<<dim3((2 * DI) / 128, nt / 128), blk, 0, stream>>>(
                abf, DM, wbf_in, DM, xz, 2 * DI, DM);

            // depthwise conv + silu, both directions
            conv_silu_k<<<dim3(((long)nt * DI + 255) / 256), blk, 0, stream>>>(
                xz, conv_w, conv_b, conv_w_b, conv_b_b, convf, convb, nt);

            // x_proj (fp32): dbl[nt,80] = conv @ x_proj_w[80,1536]^T
            gemm_nt<0><<<dim3(2, nt / 64), blk, 0, stream>>>(
                convf, DI, x_proj_w, DI, dblf, 80, nt, 80, DI, nullptr);
            gemm_nt<0><<<dim3(2, nt / 64), blk, 0, stream>>>(
                convb, DI, x_proj_w_b, DI, dblb, 80, nt, 80, DI, nullptr);

            // dt_proj (fp32): dt[nt,1536] = softplus(dbl[:, :48] @ w^T + b)
            gemm_nt<1><<<dim3(DI / 64, nt / 64), blk, 0, stream>>>(
                dblf, 80, dt_proj_w, DTR, dtf, DI, nt, DI, DTR, dt_proj_b);
            gemm_nt<1><<<dim3(DI / 64, nt / 64), blk, 0, stream>>>(
                dblb, 80, dt_proj_w_b, DTR, dtb, DI, nt, DI, DTR, dt_proj_b_b);

            // selective scan, fwd + bwd (y overwrites dt buffers)
            scan_k<<<dim3(DI / 16, cb, 2), dim3(64), 0, stream>>>(
                convf, dtf, dblf, A_log, Dp,
                convb, dtb, dblb, A_log_b, D_b);

            // gate -> bf16 A operand for out_proj
            gate_k<<<dim3(((long)nt * DI + 255) / 256), blk, 0, stream>>>(
                dtf, dtb, xz, abf, nt);

            // out_proj via MFMA: mo[nt,768] = g_bf @ wbf_out[768,1536]^T
            gemm_bf16<<<dim3(DM / 128, nt / 128), blk, 0, stream>>>(
                abf, DI, wbf_out, DI, convb, DM, DI);

            // residual + rmsnorm
            rmsnorm_res_k<<<dim3(nt), blk, 0, stream>>>(convb, xin, nw, outp);
        }
    }
}

// Round 8
// 2011.069 us; speedup vs baseline: 1.2385x; 1.2236x over previous
//
#include <hip/hip_runtime.h>
#include <hip/hip_bf16.h>
#include <math.h>

// Problem constants (from reference)
#define NB   8
#define LSEQ 1024
#define DM   768
#define DI   1536
#define NST  16
#define DTR  48
#define TT   (NB * LSEQ)   // 8192 tokens per input
#define NSEG 8             // scan segments per sequence
#define SEGL (LSEQ / NSEG) // 128 steps per segment

typedef __attribute__((ext_vector_type(8))) short bf16x8;
typedef __attribute__((ext_vector_type(4))) float f32x4;

__device__ __forceinline__ float silu_f(float x) { return x / (1.f + __expf(-x)); }
__device__ __forceinline__ float softplus_f(float x) { return x > 20.f ? x : log1pf(__expf(x)); }

// 2-lane XOR-add via DPP quad_perm 0xB1 (= perm[1,0,3,2], xor 1). Pure VALU.
__device__ __forceinline__ float dpp_xor1_add(float x) {
    int yi = __builtin_amdgcn_update_dpp(0, __float_as_int(x), 0xB1, 0xF, 0xF, true);
    return x + __int_as_float(yi);
}

// ---------------------------------------------------------------------------
// fp32 -> bf16 conversion (n must be a multiple of 4)
// ---------------------------------------------------------------------------
__global__ __launch_bounds__(256) void f2bf_k(
    const float* __restrict__ in, __hip_bfloat16* __restrict__ out, long n4)
{
    const long i = (long)blockIdx.x * 256 + threadIdx.x;
    if (i >= n4) return;
    const float4 v = ((const float4*)in)[i];
    out[i * 4 + 0] = __float2bfloat16(v.x);
    out[i * 4 + 1] = __float2bfloat16(v.y);
    out[i * 4 + 2] = __float2bfloat16(v.z);
    out[i * 4 + 3] = __float2bfloat16(v.w);
}

// ---------------------------------------------------------------------------
// bf16 MFMA GEMM: C[M,N] (fp32) = A[M,K] @ Bw[N,K]^T, A/Bw bf16 row-major.
// 128x128 tile, BK=32, 4 waves, 4x4 16x16x32 fragments per wave.
// ---------------------------------------------------------------------------
__global__ __launch_bounds__(256) void gemm_bf16(
    const __hip_bfloat16* __restrict__ A, int lda,
    const __hip_bfloat16* __restrict__ Bw, int ldb,
    float* __restrict__ C, int ldc, int K)
{
    __shared__ short lds[2][8192];      // [buf][ A 128x32 | B 128x32 ] bf16
    const int tid = threadIdx.x;
    const int lane = tid & 63;
    const int wv = tid >> 6;
    const int wm = wv >> 1;             // 0..1
    const int wn = wv & 1;              // 0..1
    const long m0 = (long)blockIdx.y * 128;
    const long n0 = (long)blockIdx.x * 128;

    const int srow = tid >> 2;          // 0..63
    const int skslot = tid & 3;
    const int sswz = skslot ^ ((srow >> 1) & 3);
    const __hip_bfloat16* gA0 = A  + (m0 + srow) * (long)lda + skslot * 8;
    const __hip_bfloat16* gA1 = gA0 + 64l * lda;
    const __hip_bfloat16* gB0 = Bw + (n0 + srow) * (long)ldb + skslot * 8;
    const __hip_bfloat16* gB1 = gB0 + 64l * ldb;
    const int wA0 = srow * 32 + sswz * 8;
    const int wA1 = (srow + 64) * 32 + sswz * 8;
    const int wB0 = 4096 + srow * 32 + sswz * 8;
    const int wB1 = 4096 + (srow + 64) * 32 + sswz * 8;

    const int frow = lane & 15;         // fragment row-in-16
    const int fk = lane >> 4;           // fragment k-slot 0..3

    f32x4 acc[4][4] = {};

    const int NK = K / 32;
    int4 r0, r1, r2, r3;
    r0 = *(const int4*)gA0; r1 = *(const int4*)gA1;
    r2 = *(const int4*)gB0; r3 = *(const int4*)gB1;
    *(int4*)&lds[0][wA0] = r0; *(int4*)&lds[0][wA1] = r1;
    *(int4*)&lds[0][wB0] = r2; *(int4*)&lds[0][wB1] = r3;

    for (int ks = 0; ks < NK; ks++) {
        const int cur = ks & 1;
        if (ks + 1 < NK) {              // issue next tile's global loads early
            const long ko = (long)(ks + 1) * 32;
            r0 = *(const int4*)(gA0 + ko); r1 = *(const int4*)(gA1 + ko);
            r2 = *(const int4*)(gB0 + ko); r3 = *(const int4*)(gB1 + ko);
        }
        __syncthreads();                // staging of `cur` visible to all
        bf16x8 af[4], bfr[4];
        #pragma unroll
        for (int mf = 0; mf < 4; mf++) {
            const int row = wm * 64 + mf * 16 + frow;
            const int sl = fk ^ ((row >> 1) & 3);
            af[mf] = *(const bf16x8*)&lds[cur][row * 32 + sl * 8];
        }
        #pragma unroll
        for (int nf = 0; nf < 4; nf++) {
            const int row = wn * 64 + nf * 16 + frow;
            const int sl = fk ^ ((row >> 1) & 3);
            bfr[nf] = *(const bf16x8*)&lds[cur][4096 + row * 32 + sl * 8];
        }
        #pragma unroll
        for (int mf = 0; mf < 4; mf++)
            #pragma unroll
            for (int nf = 0; nf < 4; nf++)
                acc[mf][nf] = __builtin_amdgcn_mfma_f32_16x16x32_bf16(
                    af[mf], bfr[nf], acc[mf][nf], 0, 0, 0);
        if (ks + 1 < NK) {              // write next tile into other buffer
            const int nb = cur ^ 1;
            *(int4*)&lds[nb][wA0] = r0; *(int4*)&lds[nb][wA1] = r1;
            *(int4*)&lds[nb][wB0] = r2; *(int4*)&lds[nb][wB1] = r3;
        }
    }

    // epilogue: C/D layout col=lane&15, row=(lane>>4)*4+j  [m89-verified]
    #pragma unroll
    for (int mf = 0; mf < 4; mf++) {
        #pragma unroll
        for (int nf = 0; nf < 4; nf++) {
            const long col = n0 + wn * 64 + nf * 16 + (lane & 15);
            const long rw = m0 + wm * 64 + mf * 16 + (lane >> 4) * 4;
            float* cp = C + rw * ldc + col;
            #pragma unroll
            for (int j = 0; j < 4; j++)
                cp[(long)j * ldc] = acc[mf][nf][j];
        }
    }
}

// ---------------------------------------------------------------------------
// Generic fp32 GEMM (kept for x_proj / dt_proj): C = A @ Bw^T
// EPI: 0 = none, 1 = softplus(x + bias[n])
// ---------------------------------------------------------------------------
template <int EPI>
__global__ __launch_bounds__(256) void gemm_nt(
    const float* __restrict__ A, int lda,
    const float* __restrict__ Bw, int ldb,
    float* __restrict__ C, int ldc,
    int M, int N, int K,
    const float* __restrict__ bias)
{
    __shared__ float As[16][68];
    __shared__ float Bs[16][68];
    const int tid = threadIdx.x;
    const int m0 = blockIdx.y * 64;
    const int n0 = blockIdx.x * 64;
    const int tx = tid & 15;
    const int ty = tid >> 4;
    const int lrow = tid >> 2;
    const int lk4 = (tid & 3) << 2;

    float acc[4][4] = {};

    for (int k0 = 0; k0 < K; k0 += 16) {
        float4 av = make_float4(0.f, 0.f, 0.f, 0.f);
        float4 bv = make_float4(0.f, 0.f, 0.f, 0.f);
        const int arow = m0 + lrow;
        if (arow < M)
            av = *reinterpret_cast<const float4*>(A + (long)arow * lda + k0 + lk4);
        const int brow = n0 + lrow;
        if (brow < N)
            bv = *reinterpret_cast<const float4*>(Bw + (long)brow * ldb + k0 + lk4);
        __syncthreads();
        As[lk4 + 0][lrow] = av.x; As[lk4 + 1][lrow] = av.y;
        As[lk4 + 2][lrow] = av.z; As[lk4 + 3][lrow] = av.w;
        Bs[lk4 + 0][lrow] = bv.x; Bs[lk4 + 1][lrow] = bv.y;
        Bs[lk4 + 2][lrow] = bv.z; Bs[lk4 + 3][lrow] = bv.w;
        __syncthreads();
        #pragma unroll
        for (int k = 0; k < 16; k++) {
            float a[4], b[4];
            #pragma unroll
            for (int i = 0; i < 4; i++) a[i] = As[k][ty * 4 + i];
            #pragma unroll
            for (int j = 0; j < 4; j++) b[j] = Bs[k][tx * 4 + j];
            #pragma unroll
            for (int i = 0; i < 4; i++)
                #pragma unroll
                for (int j = 0; j < 4; j++)
                    acc[i][j] = fmaf(a[i], b[j], acc[i][j]);
        }
    }

    #pragma unroll
    for (int i = 0; i < 4; i++) {
        const int m = m0 + ty * 4 + i;
        if (m >= M) continue;
        #pragma unroll
        for (int j = 0; j < 4; j++) {
            const int n = n0 + tx * 4 + j;
            if (n >= N) continue;
            float v = acc[i][j];
            if (EPI == 1) v = softplus_f(v + bias[n]);
            C[(long)m * ldc + n] = v;
        }
    }
}

// ---------------------------------------------------------------------------
// Depthwise causal conv (fwd) + anticausal conv (bwd), + bias + SiLU.
// ---------------------------------------------------------------------------
__global__ __launch_bounds__(256) void conv_silu_k(
    const float* __restrict__ xz,
    const float* __restrict__ cw, const float* __restrict__ cb,
    const float* __restrict__ cwb, const float* __restrict__ cbb,
    float* __restrict__ outf, float* __restrict__ outb, int nt)
{
    const long idx = (long)blockIdx.x * 256 + threadIdx.x;
    if (idx >= (long)nt * DI) return;
    const int d = (int)(idx % DI);
    const long t = idx / DI;
    const int l = (int)(t % LSEQ);
    const float* base = xz + t * (2 * DI) + d;

    float af = cb[d];
    float ab = cbb[d];
    #pragma unroll
    for (int k = 0; k < 4; k++) {
        const int dl = k - 3;
        if (l + dl >= 0) af += cw[d * 4 + k] * base[(long)dl * (2 * DI)];
        const int dl2 = 3 - k;
        if (l + dl2 < LSEQ) ab += cwb[d * 4 + k] * base[(long)dl2 * (2 * DI)];
    }
    outf[idx] = silu_f(af);
    outb[idx] = silu_f(ab);
}

// ---------------------------------------------------------------------------
// Segmented selective scan — pass A.
// Recurrence h(t) = a(t) h(t-1) + b(t) with diagonal a = exp(dt*A), so a
// segment's transfer function is h_out = E*h_in + F with E = exp(A*sum_dt)
// (exact) and F = segment scan from h=0.
// One wave per (b, dir, 32-channel group, segment): lane = (chl<<1)|sub,
// sub in {0,1} owns 8 states. 128 steps per segment, TS=8 double-buffered
// register tiles for u/dt, B staged in wave-private LDS. Writes E, F.
// Grid: (48*NSEG, cb, 2). EF layout: ((b*2+dir)*NSEG+seg)*DI*NST + d*NST + n.
// ---------------------------------------------------------------------------
__global__ __launch_bounds__(64) void scanA_k(
    const float* __restrict__ uf, const float* __restrict__ dtf, const float* __restrict__ dblf,
    const float* __restrict__ Alf,
    const float* __restrict__ ub, const float* __restrict__ dtb, const float* __restrict__ dblb,
    const float* __restrict__ Alb,
    float* __restrict__ Ebuf, float* __restrict__ Fbuf)
{
    const int dir = blockIdx.z;
    const float* u_   = dir ? ub   : uf;
    const float* dt_  = dir ? dtb  : dtf;
    const float* dbl_ = dir ? dblb : dblf;
    const float* Al   = dir ? Alb  : Alf;

    const int lane = threadIdx.x;
    const int sub = lane & 1;
    const int chl = lane >> 1;
    const int dgrp = blockIdx.x >> 3;
    const int seg = blockIdx.x & (NSEG - 1);
    const int d = dgrp * 32 + chl;
    const int b = blockIdx.y;

    __shared__ float bc[2][8][16];   // B only, per tile

    float An[8];
    #pragma unroll
    for (int k = 0; k < 8; k++) An[k] = -__expf(Al[d * NST + sub * 8 + k]);

    float h[8] = {};
    float sumdt = 0.f;
    const long tbase = (long)b * LSEQ;
    const int stp = dir ? -1 : 1;
    const int l0  = dir ? (LSEQ - 1) : 0;
    const int s0  = seg * SEGL;

#define TOKI(s) (tbase + l0 + (long)(s) * stp)

#define STAGEA(buf, tile) {                                             \
    _Pragma("unroll")                                                   \
    for (int r = 0; r < 2; r++) {                                       \
        const int e = r * 64 + lane;                                    \
        const int tok = e >> 4; const int j = e & 15;                   \
        bc[buf][tok][j] = dbl_[TOKI(s0 + (tile) * 8 + tok) * 80 + DTR + j]; } }

#define LOADA(U, DT, tile) {                                            \
    _Pragma("unroll")                                                   \
    for (int i = 0; i < 8; i++) {                                       \
        const long t = TOKI(s0 + (tile) * 8 + i);                       \
        U[i] = u_[t * DI + d]; DT[i] = dt_[t * DI + d]; } }

#define COMPA(U, DT, buf) {                                             \
    _Pragma("unroll")                                                   \
    for (int i = 0; i < 8; i++) {                                       \
        const float dtv = DT[i]; const float dtu = dtv * U[i];          \
        sumdt += dtv;                                                   \
        const float4 B0 = *(const float4*)&bc[buf][i][sub * 8];         \
        const float4 B1 = *(const float4*)&bc[buf][i][sub * 8 + 4];     \
        h[0] = h[0] * __expf(dtv * An[0]) + dtu * B0.x;                 \
        h[1] = h[1] * __expf(dtv * An[1]) + dtu * B0.y;                 \
        h[2] = h[2] * __expf(dtv * An[2]) + dtu * B0.z;                 \
        h[3] = h[3] * __expf(dtv * An[3]) + dtu * B0.w;                 \
        h[4] = h[4] * __expf(dtv * An[4]) + dtu * B1.x;                 \
        h[5] = h[5] * __expf(dtv * An[5]) + dtu * B1.y;                 \
        h[6] = h[6] * __expf(dtv * An[6]) + dtu * B1.z;                 \
        h[7] = h[7] * __expf(dtv * An[7]) + dtu * B1.w; } }

    float uA[8], dA[8], uB[8], dB[8];
    LOADA(uA, dA, 0); STAGEA(0, 0);
    for (int t2 = 0; t2 < SEGL / 8; t2 += 2) {
        if (t2 + 1 < SEGL / 8) { LOADA(uB, dB, t2 + 1); STAGEA(1, t2 + 1); }
        COMPA(uA, dA, 0);
        if (t2 + 2 < SEGL / 8) { LOADA(uA, dA, t2 + 2); STAGEA(0, t2 + 2); }
        COMPA(uB, dB, 1);
    }
    const long ef = ((long)(b * 2 + dir) * NSEG + seg) * DI * NST + (long)d * NST + sub * 8;
    #pragma unroll
    for (int k = 0; k < 8; k++) {
        Ebuf[ef + k] = __expf(An[k] * sumdt);
        Fbuf[ef + k] = h[k];
    }
#undef STAGEA
#undef LOADA
#undef COMPA
}

// ---------------------------------------------------------------------------
// Propagate: serial over NSEG segments per (b,dir,d,n). Overwrites F with
// the segment's incoming state h_in.
// ---------------------------------------------------------------------------
__global__ __launch_bounds__(256) void scan_prop_k(
    const float* __restrict__ Ebuf, float* __restrict__ Fbuf, long total)
{
    const long idx = (long)blockIdx.x * 256 + threadIdx.x;
    if (idx >= total) return;                     // total = cb*2*DI*NST
    const long bd = idx / ((long)DI * NST);
    const long r = idx % ((long)DI * NST);
    float hin = 0.f;
    #pragma unroll
    for (int s = 0; s < NSEG; s++) {
        const long o = (bd * NSEG + s) * (long)DI * NST + r;
        const float e = Ebuf[o];
        const float f = Fbuf[o];
        Fbuf[o] = hin;                            // h_in for segment s
        hin = e * hin + f;
    }
}

// ---------------------------------------------------------------------------
// Segmented selective scan — pass B. Re-scans each segment from the correct
// h_in (read from Fbuf), computes y = C.h + D*u, writes y IN PLACE over dt.
// (Loads of tile k+1 are issued before stores of tile k; disjoint tokens.)
// ---------------------------------------------------------------------------
__global__ __launch_bounds__(64) void scanB_k(
    const float* __restrict__ uf, float* __restrict__ yf, const float* __restrict__ dblf,
    const float* __restrict__ Alf, const float* __restrict__ Df,
    const float* __restrict__ ub, float* __restrict__ yb, const float* __restrict__ dblb,
    const float* __restrict__ Alb, const float* __restrict__ Db,
    const float* __restrict__ Hin)
{
    const int dir = blockIdx.z;
    const float* u_   = dir ? ub   : uf;
    float*       y_   = dir ? yb   : yf;
    const float* dbl_ = dir ? dblb : dblf;
    const float* Al   = dir ? Alb  : Alf;
    const float* Dp   = dir ? Db   : Df;

    const int lane = threadIdx.x;
    const int sub = lane & 1;
    const int chl = lane >> 1;
    const int dgrp = blockIdx.x >> 3;
    const int seg = blockIdx.x & (NSEG - 1);
    const int d = dgrp * 32 + chl;
    const int b = blockIdx.y;

    __shared__ float bc[2][8][32];   // B(16) | C(16) per tile token

    float An[8];
    #pragma unroll
    for (int k = 0; k < 8; k++) An[k] = -__expf(Al[d * NST + sub * 8 + k]);
    const float Dd = Dp[d];

    const long tbase = (long)b * LSEQ;
    const int stp = dir ? -1 : 1;
    const int l0  = dir ? (LSEQ - 1) : 0;
    const int s0  = seg * SEGL;

    float h[8];
    const long ef = ((long)(b * 2 + dir) * NSEG + seg) * DI * NST + (long)d * NST + sub * 8;
    #pragma unroll
    for (int k = 0; k < 8; k++) h[k] = Hin[ef + k];

#define STAGEB(buf, tile) {                                             \
    _Pragma("unroll")                                                   \
    for (int r = 0; r < 4; r++) {                                       \
        const int e = r * 64 + lane;                                    \
        const int tok = e >> 5; const int j = e & 31;                   \
        bc[buf][tok][j] = dbl_[TOKI(s0 + (tile) * 8 + tok) * 80 + DTR + j]; } }

#define LOADB(U, DT, tile) {                                            \
    _Pragma("unroll")                                                   \
    for (int i = 0; i < 8; i++) {                                       \
        const long t = TOKI(s0 + (tile) * 8 + i);                       \
        U[i] = u_[t * DI + d]; DT[i] = y_[t * DI + d]; } }

#define COMPB(U, DT, buf, tile) {                                       \
    _Pragma("unroll")                                                   \
    for (int i = 0; i < 8; i++) {                                       \
        const float dtv = DT[i]; const float dtu = dtv * U[i];          \
        const float4 B0 = *(const float4*)&bc[buf][i][sub * 8];         \
        const float4 B1 = *(const float4*)&bc[buf][i][sub * 8 + 4];     \
        const float4 C0 = *(const float4*)&bc[buf][i][16 + sub * 8];    \
        const float4 C1 = *(const float4*)&bc[buf][i][16 + sub * 8 + 4];\
        h[0] = h[0] * __expf(dtv * An[0]) + dtu * B0.x;                 \
        h[1] = h[1] * __expf(dtv * An[1]) + dtu * B0.y;                 \
        h[2] = h[2] * __expf(dtv * An[2]) + dtu * B0.z;                 \
        h[3] = h[3] * __expf(dtv * An[3]) + dtu * B0.w;                 \
        h[4] = h[4] * __expf(dtv * An[4]) + dtu * B1.x;                 \
        h[5] = h[5] * __expf(dtv * An[5]) + dtu * B1.y;                 \
        h[6] = h[6] * __expf(dtv * An[6]) + dtu * B1.z;                 \
        h[7] = h[7] * __expf(dtv * An[7]) + dtu * B1.w;                 \
        float p = h[0] * C0.x + h[1] * C0.y + h[2] * C0.z + h[3] * C0.w \
                + h[4] * C1.x + h[5] * C1.y + h[6] * C1.z + h[7] * C1.w;\
        p = dpp_xor1_add(p);                                            \
        if (sub == 0) {                                                 \
            const long t = TOKI(s0 + (tile) * 8 + i);                   \
            y_[t * DI + d] = p + U[i] * Dd; } } }

    float uA[8], dA[8], uB[8], dB[8];
    LOADB(uA, dA, 0); STAGEB(0, 0);
    for (int t2 = 0; t2 < SEGL / 8; t2 += 2) {
        if (t2 + 1 < SEGL / 8) { LOADB(uB, dB, t2 + 1); STAGEB(1, t2 + 1); }
        COMPB(uA, dA, 0, t2);
        if (t2 + 2 < SEGL / 8) { LOADB(uA, dA, t2 + 2); STAGEB(0, t2 + 2); }
        COMPB(uB, dB, 1, t2 + 1);
    }
#undef STAGEB
#undef LOADB
#undef COMPB
#undef TOKI
}

// ---------------------------------------------------------------------------
// Gate: g = (yf + yb) * silu(z) -> bf16 (feeds out_proj MFMA GEMM)
// ---------------------------------------------------------------------------
__global__ __launch_bounds__(256) void gate_k(
    const float* __restrict__ yf, const float* __restrict__ yb,
    const float* __restrict__ xz, __hip_bfloat16* __restrict__ g, int nt)
{
    const long idx = (long)blockIdx.x * 256 + threadIdx.x;
    if (idx >= (long)nt * DI) return;
    const int d = (int)(idx % DI);
    const long t = idx / DI;
    const float z = xz[t * (2 * DI) + DI + d];
    g[idx] = __float2bfloat16((yf[idx] + yb[idx]) * silu_f(z));
}

// ---------------------------------------------------------------------------
// out = xin + rmsnorm(mo, w);  one block per token
// ---------------------------------------------------------------------------
__global__ __launch_bounds__(256) void rmsnorm_res_k(
    const float* __restrict__ mo, const float* __restrict__ xin,
    const float* __restrict__ w, float* __restrict__ out)
{
    const int t = blockIdx.x;
    const int tid = threadIdx.x;
    const long base = (long)t * DM;
    const float v0 = mo[base + tid];
    const float v1 = mo[base + tid + 256];
    const float v2 = mo[base + tid + 512];
    float ss = v0 * v0 + v1 * v1 + v2 * v2;
    #pragma unroll
    for (int m = 1; m < 64; m <<= 1) ss += __shfl_xor(ss, m, 64);
    __shared__ float red[4];
    if ((tid & 63) == 0) red[tid >> 6] = ss;
    __syncthreads();
    const float tot = red[0] + red[1] + red[2] + red[3];
    const float sc = rsqrtf(tot * (1.f / DM) + 1e-5f);
    out[base + tid]       = xin[base + tid]       + v0 * sc * w[tid];
    out[base + tid + 256] = xin[base + tid + 256] + v1 * sc * w[tid + 256];
    out[base + tid + 512] = xin[base + tid + 512] + v2 * sc * w[tid + 512];
}

// ---------------------------------------------------------------------------
extern "C" void kernel_launch(void* const* d_in, const int* in_sizes, int n_in,
                              void* d_out, int out_size, void* d_ws, size_t ws_size,
                              hipStream_t stream)
{
    const float* m_x         = (const float*)d_in[0];
    const float* n_x         = (const float*)d_in[1];
    const float* in_proj_w   = (const float*)d_in[2];
    const float* conv_w      = (const float*)d_in[3];
    const float* conv_b      = (const float*)d_in[4];
    const float* x_proj_w    = (const float*)d_in[5];
    const float* dt_proj_w   = (const float*)d_in[6];
    const float* dt_proj_b   = (const float*)d_in[7];
    const float* A_log       = (const float*)d_in[8];
    const float* Dp          = (const float*)d_in[9];
    const float* conv_w_b    = (const float*)d_in[10];
    const float* conv_b_b    = (const float*)d_in[11];
    const float* x_proj_w_b  = (const float*)d_in[12];
    const float* dt_proj_w_b = (const float*)d_in[13];
    const float* dt_proj_b_b = (const float*)d_in[14];
    const float* A_log_b     = (const float*)d_in[15];
    const float* D_b         = (const float*)d_in[16];
    const float* out_proj_w  = (const float*)d_in[17];
    const float* norm1_w     = (const float*)d_in[18];
    const float* norm2_w     = (const float*)d_in[19];

    // ---- workspace layout: fixed bf16 weight copies first, then per-chunk
    const long W_IN  = (long)(2 * DI) * DM;   // 2,359,296 elements
    const long W_OUT = (long)DM * DI;         // 1,179,648 elements
    char* wsc = (char*)d_ws;
    __hip_bfloat16* wbf_in  = (__hip_bfloat16*)wsc;
    __hip_bfloat16* wbf_out = wbf_in + W_IN;
    char* chunk_base = (char*)(wbf_out + W_OUT);
    const size_t fixed_bytes = (size_t)(W_IN + W_OUT) * 2;

    // per-batch floats: xz 3072 + convf/b 2*1536 + dblf/b 2*80 + dtf/b 2*1536
    //  + abf (1536 bf16 = 768 f32-eq) per token, + E/F: 2*2*NSEG*DI*NST floats
    const long EFB = 2l * NSEG * DI * NST;                 // per batch, per array
    const long PBF = (long)LSEQ * (3072 + 2 * 1536 + 2 * 80 + 2 * 1536 + 768)
                   + 2 * EFB;
    int CB = (int)((ws_size - fixed_bytes) / ((size_t)PBF * 4));
    if (CB < 1) CB = 1;
    if (CB > NB) CB = NB;

    const long CT = (long)CB * LSEQ;
    float* fb    = (float*)chunk_base;
    float* xz    = fb;                       // CT * 3072
    float* convf = xz    + CT * 2 * DI;      // CT * 1536
    float* convb = convf + CT * DI;          // CT * 1536
    float* dblf  = convb + CT * DI;          // CT * 80
    float* dblb  = dblf  + CT * 80;          // CT * 80
    float* dtf   = dblb  + CT * 80;          // CT * 1536 (scanB -> yf in place)
    float* dtb   = dtf   + CT * DI;          // CT * 1536 (scanB -> yb in place)
    __hip_bfloat16* abf = (__hip_bfloat16*)(dtb + CT * DI);  // CT * 1536 bf16
    float* Ebuf = (float*)(abf + CT * DI);   // CB * EFB
    float* Fbuf = Ebuf + (long)CB * EFB;     // CB * EFB

    const dim3 blk(256);

    // convert projection weights to bf16 once
    f2bf_k<<<dim3((W_IN / 4 + 255) / 256), blk, 0, stream>>>(in_proj_w, wbf_in, W_IN / 4);
    f2bf_k<<<dim3((W_OUT / 4 + 255) / 256), blk, 0, stream>>>(out_proj_w, wbf_out, W_OUT / 4);

    for (int which = 0; which < 2; which++) {
        const float* xin0 = which ? n_x : m_x;
        const float* nw   = which ? norm2_w : norm1_w;
        float* out0 = (float*)d_out + (long)which * TT * DM;

        for (int b0 = 0; b0 < NB; b0 += CB) {
            const int cb = (NB - b0) < CB ? (NB - b0) : CB;
            const int nt = cb * LSEQ;
            const float* xin = xin0 + (long)b0 * LSEQ * DM;
            float* outp = out0 + (long)b0 * LSEQ * DM;

            // A -> bf16, then in_proj via MFMA:
            f2bf_k<<<dim3(((long)nt * DM / 4 + 255) / 256), blk, 0, stream>>>(
                xin, abf, (long)nt * DM / 4);
            gemm_bf16<<<dim3((2 * DI) / 128, nt / 128), blk, 0, stream>>>(
                abf, DM, wbf_in, DM, xz, 2 * DI, DM);

            // depthwise conv + silu, both directions
            conv_silu_k<<<dim3(((long)nt * DI + 255) / 256), blk, 0, stream>>>(
                xz, conv_w, conv_b, conv_w_b, conv_b_b, convf, convb, nt);

            // x_proj (fp32): dbl[nt,80] = conv @ x_proj_w[80,1536]^T
            gemm_nt<0><<<dim3(2, nt / 64), blk, 0, stream>>>(
                convf, DI, x_proj_w, DI, dblf, 80, nt, 80, DI, nullptr);
            gemm_nt<0><<<dim3(2, nt / 64), blk, 0, stream>>>(
                convb, DI, x_proj_w_b, DI, dblb, 80, nt, 80, DI, nullptr);

            // dt_proj (fp32): dt[nt,1536] = softplus(dbl[:, :48] @ w^T + b)
            gemm_nt<1><<<dim3(DI / 64, nt / 64), blk, 0, stream>>>(
                dblf, 80, dt_proj_w, DTR, dtf, DI, nt, DI, DTR, dt_proj_b);
            gemm_nt<1><<<dim3(DI / 64, nt / 64), blk, 0, stream>>>(
                dblb, 80, dt_proj_w_b, DTR, dtb, DI, nt, DI, DTR, dt_proj_b_b);

            // segmented scan: pass A -> propagate -> pass B (y in place)
            scanA_k<<<dim3((DI / 32) * NSEG, cb, 2), dim3(64), 0, stream>>>(
                convf, dtf, dblf, A_log, convb, dtb, dblb, A_log_b, Ebuf, Fbuf);
            const long ptotal = (long)cb * 2 * DI * NST;
            scan_prop_k<<<dim3((ptotal + 255) / 256), blk, 0, stream>>>(
                Ebuf, Fbuf, ptotal);
            scanB_k<<<dim3((DI / 32) * NSEG, cb, 2), dim3(64), 0, stream>>>(
                convf, dtf, dblf, A_log, Dp, convb, dtb, dblb, A_log_b, D_b, Fbuf);

            // gate -> bf16 A operand for out_proj
            gate_k<<<dim3(((long)nt * DI + 255) / 256), blk, 0, stream>>>(
                dtf, dtb, xz, abf, nt);

            // out_proj via MFMA: mo[nt,768] = g_bf @ wbf_out[768,1536]^T
            gemm_bf16<<<dim3(DM / 128, nt / 128), blk, 0, stream>>>(
                abf, DI, wbf_out, DI, convb, DM, DI);

            // residual + rmsnorm
            rmsnorm_res_k<<<dim3(nt), blk, 0, stream>>>(convb, xin, nw, outp);
        }
    }
}

// Round 9
// 1618.424 us; speedup vs baseline: 1.5390x; 1.2426x over previous
//
#include <hip/hip_runtime.h>
#include <hip/hip_bf16.h>
#include <math.h>

// Problem constants (from reference)
#define NB   8
#define LSEQ 1024
#define DM   768
#define DI   1536
#define NST  16
#define DTR  48
#define TT   (NB * LSEQ)   // 8192 tokens per input
#define NSEG 16            // scan segments per sequence
#define SEGL (LSEQ / NSEG) // 64 steps per segment
#define DTRP 64            // padded dt_rank for MFMA (48 -> 64)

typedef __attribute__((ext_vector_type(8))) short bf16x8;
typedef __attribute__((ext_vector_type(4))) float f32x4;

__device__ __forceinline__ float silu_f(float x) { return x / (1.f + __expf(-x)); }
__device__ __forceinline__ float softplus_f(float x) { return x > 20.f ? x : log1pf(__expf(x)); }

// 2-lane XOR-add via DPP quad_perm 0xB1 (= perm[1,0,3,2], xor 1). Pure VALU.
__device__ __forceinline__ float dpp_xor1_add(float x) {
    int yi = __builtin_amdgcn_update_dpp(0, __float_as_int(x), 0xB1, 0xF, 0xF, true);
    return x + __int_as_float(yi);
}

// ---------------------------------------------------------------------------
// fp32 -> bf16 conversion (n multiple of 4)
// ---------------------------------------------------------------------------
__global__ __launch_bounds__(256) void f2bf_k(
    const float* __restrict__ in, __hip_bfloat16* __restrict__ out, long n4)
{
    const long i = (long)blockIdx.x * 256 + threadIdx.x;
    if (i >= n4) return;
    const float4 v = ((const float4*)in)[i];
    out[i * 4 + 0] = __float2bfloat16(v.x);
    out[i * 4 + 1] = __float2bfloat16(v.y);
    out[i * 4 + 2] = __float2bfloat16(v.z);
    out[i * 4 + 3] = __float2bfloat16(v.w);
}

// fp32 [rows, ic] -> bf16 [rows, oc] zero-padded
__global__ __launch_bounds__(256) void f2bf_pad_k(
    const float* __restrict__ in, __hip_bfloat16* __restrict__ out,
    int rows, int ic, int oc)
{
    const int i = blockIdx.x * 256 + threadIdx.x;
    if (i >= rows * oc) return;
    const int r = i / oc, c = i % oc;
    out[i] = __float2bfloat16(c < ic ? in[r * ic + c] : 0.f);
}

// ---------------------------------------------------------------------------
// MFMA bf16 GEMM, C[M,N](fp32) = A[M,K] @ Bw[N,K]^T. 128x128 tile, BK=32,
// 4 waves, 4x4 16x16x32 frags. Dir-fused via blockIdx.z (selects *0/*1 ptrs).
// MODE 0: plain.
// MODE 1: x_proj — N=80 (row-guarded B staging, col<N store guard) and also
//         writes dtr[row*DTRP+col] = bf16(v) for col<48, 0 for 48<=col<64.
// MODE 2: dt_proj — epilogue v = softplus(v + bias[col]).
// Requires M%128==0, K%32==0; N%128==0 unless MODE==1.
// ---------------------------------------------------------------------------
template <int MODE>
__global__ __launch_bounds__(256) void gemm_mf_k(
    const __hip_bfloat16* __restrict__ A0, const __hip_bfloat16* __restrict__ A1, int lda,
    const __hip_bfloat16* __restrict__ B0, const __hip_bfloat16* __restrict__ B1, int ldb,
    float* __restrict__ C0, float* __restrict__ C1, int ldc,
    int K, int N,
    const float* __restrict__ bias0, const float* __restrict__ bias1,
    __hip_bfloat16* __restrict__ dtr0, __hip_bfloat16* __restrict__ dtr1)
{
    const int dir = blockIdx.z;
    const __hip_bfloat16* A  = dir ? A1 : A0;
    const __hip_bfloat16* Bw = dir ? B1 : B0;
    float* C = dir ? C1 : C0;
    const float* bias = dir ? bias1 : bias0;
    __hip_bfloat16* dtr = dir ? dtr1 : dtr0;

    __shared__ short lds[2][8192];      // [buf][ A 128x32 | B 128x32 ] bf16
    const int tid = threadIdx.x;
    const int lane = tid & 63;
    const int wv = tid >> 6;
    const int wm = wv >> 1;
    const int wn = wv & 1;
    const long m0 = (long)blockIdx.y * 128;
    const long n0 = (long)blockIdx.x * 128;

    const int srow = tid >> 2;          // 0..63
    const int skslot = tid & 3;
    const int sswz = skslot ^ ((srow >> 1) & 3);
    const __hip_bfloat16* gA0 = A  + (m0 + srow) * (long)lda + skslot * 8;
    const __hip_bfloat16* gA1 = gA0 + 64l * lda;
    const __hip_bfloat16* gB0 = Bw + (n0 + srow) * (long)ldb + skslot * 8;
    const __hip_bfloat16* gB1 = gB0 + 64l * ldb;
    const bool bv0 = (MODE != 1) || (n0 + srow < N);
    const bool bv1 = (MODE != 1) || (n0 + srow + 64 < N);
    const int wA0 = srow * 32 + sswz * 8;
    const int wA1 = (srow + 64) * 32 + sswz * 8;
    const int wB0 = 4096 + srow * 32 + sswz * 8;
    const int wB1 = 4096 + (srow + 64) * 32 + sswz * 8;

    const int frow = lane & 15;
    const int fk = lane >> 4;

    f32x4 acc[4][4] = {};
    const int4 zero4 = make_int4(0, 0, 0, 0);

    const int NK = K / 32;
    int4 r0, r1, r2, r3;
    r0 = *(const int4*)gA0; r1 = *(const int4*)gA1;
    r2 = bv0 ? *(const int4*)gB0 : zero4;
    r3 = bv1 ? *(const int4*)gB1 : zero4;
    *(int4*)&lds[0][wA0] = r0; *(int4*)&lds[0][wA1] = r1;
    *(int4*)&lds[0][wB0] = r2; *(int4*)&lds[0][wB1] = r3;

    for (int ks = 0; ks < NK; ks++) {
        const int cur = ks & 1;
        if (ks + 1 < NK) {
            const long ko = (long)(ks + 1) * 32;
            r0 = *(const int4*)(gA0 + ko); r1 = *(const int4*)(gA1 + ko);
            r2 = bv0 ? *(const int4*)(gB0 + ko) : zero4;
            r3 = bv1 ? *(const int4*)(gB1 + ko) : zero4;
        }
        __syncthreads();
        bf16x8 af[4], bfr[4];
        #pragma unroll
        for (int mf = 0; mf < 4; mf++) {
            const int row = wm * 64 + mf * 16 + frow;
            const int sl = fk ^ ((row >> 1) & 3);
            af[mf] = *(const bf16x8*)&lds[cur][row * 32 + sl * 8];
        }
        #pragma unroll
        for (int nf = 0; nf < 4; nf++) {
            const int row = wn * 64 + nf * 16 + frow;
            const int sl = fk ^ ((row >> 1) & 3);
            bfr[nf] = *(const bf16x8*)&lds[cur][4096 + row * 32 + sl * 8];
        }
        #pragma unroll
        for (int mf = 0; mf < 4; mf++)
            #pragma unroll
            for (int nf = 0; nf < 4; nf++)
                acc[mf][nf] = __builtin_amdgcn_mfma_f32_16x16x32_bf16(
                    af[mf], bfr[nf], acc[mf][nf], 0, 0, 0);
        if (ks + 1 < NK) {
            const int nb = cur ^ 1;
            *(int4*)&lds[nb][wA0] = r0; *(int4*)&lds[nb][wA1] = r1;
            *(int4*)&lds[nb][wB0] = r2; *(int4*)&lds[nb][wB1] = r3;
        }
    }

    // epilogue: C/D layout col=lane&15, row=(lane>>4)*4+j
    #pragma unroll
    for (int mf = 0; mf < 4; mf++) {
        #pragma unroll
        for (int nf = 0; nf < 4; nf++) {
            const long col = n0 + wn * 64 + nf * 16 + (lane & 15);
            const long rw = m0 + wm * 64 + mf * 16 + (lane >> 4) * 4;
            #pragma unroll
            for (int j = 0; j < 4; j++) {
                float v = acc[mf][nf][j];
                const long row = rw + j;
                if (MODE == 2) v = softplus_f(v + bias[col]);
                if (MODE == 1) {
                    if (col < N) C[row * ldc + col] = v;
                    if (col < DTR) dtr[row * DTRP + col] = __float2bfloat16(v);
                    else if (col < DTRP) dtr[row * DTRP + col] = __float2bfloat16(0.f);
                } else {
                    C[row * ldc + col] = v;
                }
            }
        }
    }
}

// ---------------------------------------------------------------------------
// Depthwise causal conv (fwd) + anticausal conv (bwd), + bias + SiLU -> bf16
// ---------------------------------------------------------------------------
__global__ __launch_bounds__(256) void conv_silu_k(
    const float* __restrict__ xz,
    const float* __restrict__ cw, const float* __restrict__ cb,
    const float* __restrict__ cwb, const float* __restrict__ cbb,
    __hip_bfloat16* __restrict__ outf, __hip_bfloat16* __restrict__ outb, int nt)
{
    const long idx = (long)blockIdx.x * 256 + threadIdx.x;
    if (idx >= (long)nt * DI) return;
    const int d = (int)(idx % DI);
    const long t = idx / DI;
    const int l = (int)(t % LSEQ);
    const float* base = xz + t * (2 * DI) + d;

    float af = cb[d];
    float ab = cbb[d];
    #pragma unroll
    for (int k = 0; k < 4; k++) {
        const int dl = k - 3;
        if (l + dl >= 0) af += cw[d * 4 + k] * base[(long)dl * (2 * DI)];
        const int dl2 = 3 - k;
        if (l + dl2 < LSEQ) ab += cwb[d * 4 + k] * base[(long)dl2 * (2 * DI)];
    }
    outf[idx] = __float2bfloat16(silu_f(af));
    outb[idx] = __float2bfloat16(silu_f(ab));
}

// ---------------------------------------------------------------------------
// Segmented selective scan — pass A: per segment from h=0, emit E,F.
// One wave per (b, dir, 32-ch group, segment); lane=(chl<<1)|sub, 8 states.
// ---------------------------------------------------------------------------
__global__ __launch_bounds__(64) void scanA_k(
    const __hip_bfloat16* __restrict__ uf, const float* __restrict__ dtf, const float* __restrict__ dblf,
    const float* __restrict__ Alf,
    const __hip_bfloat16* __restrict__ ub, const float* __restrict__ dtb, const float* __restrict__ dblb,
    const float* __restrict__ Alb,
    float* __restrict__ Ebuf, float* __restrict__ Fbuf)
{
    const int dir = blockIdx.z;
    const __hip_bfloat16* u_ = dir ? ub : uf;
    const float* dt_  = dir ? dtb  : dtf;
    const float* dbl_ = dir ? dblb : dblf;
    const float* Al   = dir ? Alb  : Alf;

    const int lane = threadIdx.x;
    const int sub = lane & 1;
    const int chl = lane >> 1;
    const int dgrp = blockIdx.x / NSEG;
    const int seg = blockIdx.x % NSEG;
    const int d = dgrp * 32 + chl;
    const int b = blockIdx.y;

    __shared__ float bc[2][8][16];   // B only, per tile

    float An[8];
    #pragma unroll
    for (int k = 0; k < 8; k++) An[k] = -__expf(Al[d * NST + sub * 8 + k]);

    float h[8] = {};
    float sumdt = 0.f;
    const long tbase = (long)b * LSEQ;
    const int stp = dir ? -1 : 1;
    const int l0  = dir ? (LSEQ - 1) : 0;
    const int s0  = seg * SEGL;

#define TOKI(s) (tbase + l0 + (long)(s) * stp)

#define STAGEA(buf, tile) {                                             \
    _Pragma("unroll")                                                   \
    for (int r = 0; r < 2; r++) {                                       \
        const int e = r * 64 + lane;                                    \
        const int tok = e >> 4; const int j = e & 15;                   \
        bc[buf][tok][j] = dbl_[TOKI(s0 + (tile) * 8 + tok) * 80 + DTR + j]; } }

#define LOADA(U, DT, tile) {                                            \
    _Pragma("unroll")                                                   \
    for (int i = 0; i < 8; i++) {                                       \
        const long t = TOKI(s0 + (tile) * 8 + i);                       \
        U[i] = __bfloat162float(u_[t * DI + d]);                        \
        DT[i] = dt_[t * DI + d]; } }

#define COMPA(U, DT, buf) {                                             \
    _Pragma("unroll")                                                   \
    for (int i = 0; i < 8; i++) {                                       \
        const float dtv = DT[i]; const float dtu = dtv * U[i];          \
        sumdt += dtv;                                                   \
        const float4 B0 = *(const float4*)&bc[buf][i][sub * 8];         \
        const float4 B1 = *(const float4*)&bc[buf][i][sub * 8 + 4];     \
        h[0] = h[0] * __expf(dtv * An[0]) + dtu * B0.x;                 \
        h[1] = h[1] * __expf(dtv * An[1]) + dtu * B0.y;                 \
        h[2] = h[2] * __expf(dtv * An[2]) + dtu * B0.z;                 \
        h[3] = h[3] * __expf(dtv * An[3]) + dtu * B0.w;                 \
        h[4] = h[4] * __expf(dtv * An[4]) + dtu * B1.x;                 \
        h[5] = h[5] * __expf(dtv * An[5]) + dtu * B1.y;                 \
        h[6] = h[6] * __expf(dtv * An[6]) + dtu * B1.z;                 \
        h[7] = h[7] * __expf(dtv * An[7]) + dtu * B1.w; } }

    float uA[8], dA[8], uB[8], dB[8];
    LOADA(uA, dA, 0); STAGEA(0, 0);
    for (int t2 = 0; t2 < SEGL / 8; t2 += 2) {
        if (t2 + 1 < SEGL / 8) { LOADA(uB, dB, t2 + 1); STAGEA(1, t2 + 1); }
        COMPA(uA, dA, 0);
        if (t2 + 2 < SEGL / 8) { LOADA(uA, dA, t2 + 2); STAGEA(0, t2 + 2); }
        COMPA(uB, dB, 1);
    }
    const long ef = ((long)(b * 2 + dir) * NSEG + seg) * DI * NST + (long)d * NST + sub * 8;
    #pragma unroll
    for (int k = 0; k < 8; k++) {
        Ebuf[ef + k] = __expf(An[k] * sumdt);
        Fbuf[ef + k] = h[k];
    }
#undef STAGEA
#undef LOADA
#undef COMPA
}

// ---------------------------------------------------------------------------
// Propagate: serial over NSEG segments per (b,dir,d,n); F := h_in per segment.
// ---------------------------------------------------------------------------
__global__ __launch_bounds__(256) void scan_prop_k(
    const float* __restrict__ Ebuf, float* __restrict__ Fbuf, long total)
{
    const long idx = (long)blockIdx.x * 256 + threadIdx.x;
    if (idx >= total) return;                     // total = cb*2*DI*NST
    const long bd = idx / ((long)DI * NST);
    const long r = idx % ((long)DI * NST);
    float hin = 0.f;
    #pragma unroll
    for (int s = 0; s < NSEG; s++) {
        const long o = (bd * NSEG + s) * (long)DI * NST + r;
        const float e = Ebuf[o];
        const float f = Fbuf[o];
        Fbuf[o] = hin;
        hin = e * hin + f;
    }
}

// ---------------------------------------------------------------------------
// Segmented selective scan — pass B: re-scan from h_in, y in place over dt.
// ---------------------------------------------------------------------------
__global__ __launch_bounds__(64) void scanB_k(
    const __hip_bfloat16* __restrict__ uf, float* __restrict__ yf, const float* __restrict__ dblf,
    const float* __restrict__ Alf, const float* __restrict__ Df,
    const __hip_bfloat16* __restrict__ ub, float* __restrict__ yb, const float* __restrict__ dblb,
    const float* __restrict__ Alb, const float* __restrict__ Db,
    const float* __restrict__ Hin)
{
    const int dir = blockIdx.z;
    const __hip_bfloat16* u_ = dir ? ub : uf;
    float*       y_   = dir ? yb   : yf;
    const float* dbl_ = dir ? dblb : dblf;
    const float* Al   = dir ? Alb  : Alf;
    const float* Dp   = dir ? Db   : Df;

    const int lane = threadIdx.x;
    const int sub = lane & 1;
    const int chl = lane >> 1;
    const int dgrp = blockIdx.x / NSEG;
    const int seg = blockIdx.x % NSEG;
    const int d = dgrp * 32 + chl;
    const int b = blockIdx.y;

    __shared__ float bc[2][8][32];   // B(16) | C(16) per tile token

    float An[8];
    #pragma unroll
    for (int k = 0; k < 8; k++) An[k] = -__expf(Al[d * NST + sub * 8 + k]);
    const float Dd = Dp[d];

    const long tbase = (long)b * LSEQ;
    const int stp = dir ? -1 : 1;
    const int l0  = dir ? (LSEQ - 1) : 0;
    const int s0  = seg * SEGL;

    float h[8];
    const long ef = ((long)(b * 2 + dir) * NSEG + seg) * DI * NST + (long)d * NST + sub * 8;
    #pragma unroll
    for (int k = 0; k < 8; k++) h[k] = Hin[ef + k];

#define STAGEB(buf, tile) {                                             \
    _Pragma("unroll")                                                   \
    for (int r = 0; r < 4; r++) {                                       \
        const int e = r * 64 + lane;                                    \
        const int tok = e >> 5; const int j = e & 31;                   \
        bc[buf][tok][j] = dbl_[TOKI(s0 + (tile) * 8 + tok) * 80 + DTR + j]; } }

#define LOADB(U, DT, tile) {                                            \
    _Pragma("unroll")                                                   \
    for (int i = 0; i < 8; i++) {                                       \
        const long t = TOKI(s0 + (tile) * 8 + i);                       \
        U[i] = __bfloat162float(u_[t * DI + d]);                        \
        DT[i] = y_[t * DI + d]; } }

#define COMPB(U, DT, buf, tile) {                                       \
    _Pragma("unroll")                                                   \
    for (int i = 0; i < 8; i++) {                                       \
        const float dtv = DT[i]; const float dtu = dtv * U[i];          \
        const float4 B0 = *(const float4*)&bc[buf][i][sub * 8];         \
        const float4 B1 = *(const float4*)&bc[buf][i][sub * 8 + 4];     \
        const float4 C0 = *(const float4*)&bc[buf][i][16 + sub * 8];    \
        const float4 C1 = *(const float4*)&bc[buf][i][16 + sub * 8 + 4];\
        h[0] = h[0] * __expf(dtv * An[0]) + dtu * B0.x;                 \
        h[1] = h[1] * __expf(dtv * An[1]) + dtu * B0.y;                 \
        h[2] = h[2] * __expf(dtv * An[2]) + dtu * B0.z;                 \
        h[3] = h[3] * __expf(dtv * An[3]) + dtu * B0.w;                 \
        h[4] = h[4] * __expf(dtv * An[4]) + dtu * B1.x;                 \
        h[5] = h[5] * __expf(dtv * An[5]) + dtu * B1.y;                 \
        h[6] = h[6] * __expf(dtv * An[6]) + dtu * B1.z;                 \
        h[7] = h[7] * __expf(dtv * An[7]) + dtu * B1.w;                 \
        float p = h[0] * C0.x + h[1] * C0.y + h[2] * C0.z + h[3] * C0.w \
                + h[4] * C1.x + h[5] * C1.y + h[6] * C1.z + h[7] * C1.w;\
        p = dpp_xor1_add(p);                                            \
        if (sub == 0) {                                                 \
            const long t = TOKI(s0 + (tile) * 8 + i);                   \
            y_[t * DI + d] = p + U[i] * Dd; } } }

    float uA[8], dA[8], uB[8], dB[8];
    LOADB(uA, dA, 0); STAGEB(0, 0);
    for (int t2 = 0; t2 < SEGL / 8; t2 += 2) {
        if (t2 + 1 < SEGL / 8) { LOADB(uB, dB, t2 + 1); STAGEB(1, t2 + 1); }
        COMPB(uA, dA, 0, t2);
        if (t2 + 2 < SEGL / 8) { LOADB(uA, dA, t2 + 2); STAGEB(0, t2 + 2); }
        COMPB(uB, dB, 1, t2 + 1);
    }
#undef STAGEB
#undef LOADB
#undef COMPB
#undef TOKI
}

// ---------------------------------------------------------------------------
// Gate: g = (yf + yb) * silu(z) -> bf16, written into the dead xi half of xz
// (stride GS bf16 per token; z is read from fp32 cols [DI,2DI) — disjoint).
// ---------------------------------------------------------------------------
#define GS (4 * DI)   // bf16 slots per xz row
__global__ __launch_bounds__(256) void gate_k(
    const float* __restrict__ yf, const float* __restrict__ yb,
    const float* __restrict__ xz, __hip_bfloat16* __restrict__ g, int nt)
{
    const long idx = (long)blockIdx.x * 256 + threadIdx.x;
    if (idx >= (long)nt * DI) return;
    const int d = (int)(idx % DI);
    const long t = idx / DI;
    const float z = xz[t * (2 * DI) + DI + d];
    g[t * GS + d] = __float2bfloat16((yf[idx] + yb[idx]) * silu_f(z));
}

// ---------------------------------------------------------------------------
// out = xin + rmsnorm(mo, w);  one block per token
// ---------------------------------------------------------------------------
__global__ __launch_bounds__(256) void rmsnorm_res_k(
    const float* __restrict__ mo, const float* __restrict__ xin,
    const float* __restrict__ w, float* __restrict__ out)
{
    const int t = blockIdx.x;
    const int tid = threadIdx.x;
    const long base = (long)t * DM;
    const float v0 = mo[base + tid];
    const float v1 = mo[base + tid + 256];
    const float v2 = mo[base + tid + 512];
    float ss = v0 * v0 + v1 * v1 + v2 * v2;
    #pragma unroll
    for (int m = 1; m < 64; m <<= 1) ss += __shfl_xor(ss, m, 64);
    __shared__ float red[4];
    if ((tid & 63) == 0) red[tid >> 6] = ss;
    __syncthreads();
    const float tot = red[0] + red[1] + red[2] + red[3];
    const float sc = rsqrtf(tot * (1.f / DM) + 1e-5f);
    out[base + tid]       = xin[base + tid]       + v0 * sc * w[tid];
    out[base + tid + 256] = xin[base + tid + 256] + v1 * sc * w[tid + 256];
    out[base + tid + 512] = xin[base + tid + 512] + v2 * sc * w[tid + 512];
}

// ---------------------------------------------------------------------------
extern "C" void kernel_launch(void* const* d_in, const int* in_sizes, int n_in,
                              void* d_out, int out_size, void* d_ws, size_t ws_size,
                              hipStream_t stream)
{
    const float* m_x         = (const float*)d_in[0];
    const float* n_x         = (const float*)d_in[1];
    const float* in_proj_w   = (const float*)d_in[2];
    const float* conv_w      = (const float*)d_in[3];
    const float* conv_b      = (const float*)d_in[4];
    const float* x_proj_w    = (const float*)d_in[5];
    const float* dt_proj_w   = (const float*)d_in[6];
    const float* dt_proj_b   = (const float*)d_in[7];
    const float* A_log       = (const float*)d_in[8];
    const float* Dp          = (const float*)d_in[9];
    const float* conv_w_b    = (const float*)d_in[10];
    const float* conv_b_b    = (const float*)d_in[11];
    const float* x_proj_w_b  = (const float*)d_in[12];
    const float* dt_proj_w_b = (const float*)d_in[13];
    const float* dt_proj_b_b = (const float*)d_in[14];
    const float* A_log_b     = (const float*)d_in[15];
    const float* D_b         = (const float*)d_in[16];
    const float* out_proj_w  = (const float*)d_in[17];
    const float* norm1_w     = (const float*)d_in[18];
    const float* norm2_w     = (const float*)d_in[19];

    // ---- fixed bf16 weight copies
    const long W_IN  = (long)(2 * DI) * DM;
    const long W_OUT = (long)DM * DI;
    const long W_XP  = 80l * DI;
    const long W_DT  = (long)DI * DTRP;
    __hip_bfloat16* wbf_in  = (__hip_bfloat16*)d_ws;
    __hip_bfloat16* wbf_out = wbf_in  + W_IN;
    __hip_bfloat16* wxp0    = wbf_out + W_OUT;
    __hip_bfloat16* wxp1    = wxp0    + W_XP;
    __hip_bfloat16* wdt0    = wxp1    + W_XP;
    __hip_bfloat16* wdt1    = wdt0    + W_DT;
    char* chunk_base = (char*)(wdt1 + W_DT);
    const size_t fixed_bytes = (size_t)(W_IN + W_OUT + 2 * W_XP + 2 * W_DT) * 2;

    // per-batch f32-equiv: xz 3072 + conv(bf16) 1536 + dbl 160 + dtr(bf16) 64
    //                    + dt 3072 per token, + E/F 2*(2*NSEG*DI*NST)
    const long EFB = 2l * NSEG * DI * NST;                 // per batch per array
    const long PBF = (long)LSEQ * (3072 + 1536 + 160 + 64 + 3072) + 2 * EFB;
    int CB = (int)((ws_size - fixed_bytes) / ((size_t)PBF * 4));
    if (CB < 1) CB = 1;
    if (CB > NB) CB = NB;

    const long CT = (long)CB * LSEQ;
    float* xz = (float*)chunk_base;                         // CT*3072 f
    __hip_bfloat16* convf = (__hip_bfloat16*)(xz + CT * 3072);  // CT*1536 bf16
    __hip_bfloat16* convb = convf + CT * DI;                // CT*1536 bf16
    float* dblf = (float*)(convb + CT * DI);                // CT*80 f
    float* dblb = dblf + CT * 80;                           // CT*80 f
    __hip_bfloat16* dtrf = (__hip_bfloat16*)(dblb + CT * 80);   // CT*64 bf16
    __hip_bfloat16* dtrb = dtrf + CT * DTRP;                // CT*64 bf16
    float* dtf = (float*)(dtrb + CT * DTRP);                // CT*1536 f
    float* dtb = dtf + CT * DI;                             // CT*1536 f
    float* Ebuf = dtb + CT * DI;                            // CB*EFB
    float* Fbuf = Ebuf + (long)CB * EFB;                    // CB*EFB
    // aliases: xin_bf16 over (dead-until-dt_proj) dtf; g bf16 over xi half of
    // xz; mamba_out fp32 over (dead-after-scan) convf.
    __hip_bfloat16* xbf = (__hip_bfloat16*)dtf;
    __hip_bfloat16* gbf = (__hip_bfloat16*)xz;
    float* mo = (float*)convf;

    const dim3 blk(256);

    // weight conversions (once per call)
    f2bf_k<<<dim3((W_IN / 4 + 255) / 256), blk, 0, stream>>>(in_proj_w, wbf_in, W_IN / 4);
    f2bf_k<<<dim3((W_OUT / 4 + 255) / 256), blk, 0, stream>>>(out_proj_w, wbf_out, W_OUT / 4);
    f2bf_k<<<dim3((W_XP / 4 + 255) / 256), blk, 0, stream>>>(x_proj_w, wxp0, W_XP / 4);
    f2bf_k<<<dim3((W_XP / 4 + 255) / 256), blk, 0, stream>>>(x_proj_w_b, wxp1, W_XP / 4);
    f2bf_pad_k<<<dim3((DI * DTRP + 255) / 256), blk, 0, stream>>>(dt_proj_w, wdt0, DI, DTR, DTRP);
    f2bf_pad_k<<<dim3((DI * DTRP + 255) / 256), blk, 0, stream>>>(dt_proj_w_b, wdt1, DI, DTR, DTRP);

    for (int which = 0; which < 2; which++) {
        const float* xin0 = which ? n_x : m_x;
        const float* nw   = which ? norm2_w : norm1_w;
        float* out0 = (float*)d_out + (long)which * TT * DM;

        for (int b0 = 0; b0 < NB; b0 += CB) {
            const int cb = (NB - b0) < CB ? (NB - b0) : CB;
            const int nt = cb * LSEQ;
            const float* xin = xin0 + (long)b0 * LSEQ * DM;
            float* outp = out0 + (long)b0 * LSEQ * DM;

            // xin -> bf16, then in_proj (MFMA): xz = xbf @ wbf_in^T
            f2bf_k<<<dim3(((long)nt * DM / 4 + 255) / 256), blk, 0, stream>>>(
                xin, xbf, (long)nt * DM / 4);
            gemm_mf_k<0><<<dim3((2 * DI) / 128, nt / 128, 1), blk, 0, stream>>>(
                xbf, xbf, DM, wbf_in, wbf_in, DM, xz, xz, 2 * DI, DM, 2 * DI,
                nullptr, nullptr, nullptr, nullptr);

            // depthwise conv + silu -> bf16
            conv_silu_k<<<dim3(((long)nt * DI + 255) / 256), blk, 0, stream>>>(
                xz, conv_w, conv_b, conv_w_b, conv_b_b, convf, convb, nt);

            // x_proj (MFMA, both dirs): dbl fp32 + dtr bf16 (padded)
            gemm_mf_k<1><<<dim3(1, nt / 128, 2), blk, 0, stream>>>(
                convf, convb, DI, wxp0, wxp1, DI, dblf, dblb, 80, DI, 80,
                nullptr, nullptr, dtrf, dtrb);

            // dt_proj (MFMA, both dirs): dt = softplus(dtr @ wdt^T + b)
            gemm_mf_k<2><<<dim3(DI / 128, nt / 128, 2), blk, 0, stream>>>(
                dtrf, dtrb, DTRP, wdt0, wdt1, DTRP, dtf, dtb, DI, DTRP, DI,
                dt_proj_b, dt_proj_b_b, nullptr, nullptr);

            // segmented scan: pass A -> propagate -> pass B (y in place)
            scanA_k<<<dim3((DI / 32) * NSEG, cb, 2), dim3(64), 0, stream>>>(
                convf, dtf, dblf, A_log, convb, dtb, dblb, A_log_b, Ebuf, Fbuf);
            const long ptotal = (long)cb * 2 * DI * NST;
            scan_prop_k<<<dim3((ptotal + 255) / 256), blk, 0, stream>>>(
                Ebuf, Fbuf, ptotal);
            scanB_k<<<dim3((DI / 32) * NSEG, cb, 2), dim3(64), 0, stream>>>(
                convf, dtf, dblf, A_log, Dp, convb, dtb, dblb, A_log_b, D_b, Fbuf);

            // gate -> bf16 g (into dead xi half of xz)
            gate_k<<<dim3(((long)nt * DI + 255) / 256), blk, 0, stream>>>(
                dtf, dtb, xz, gbf, nt);

            // out_proj (MFMA): mo = g @ wbf_out^T
            gemm_mf_k<0><<<dim3(DM / 128, nt / 128, 1), blk, 0, stream>>>(
                gbf, gbf, GS, wbf_out, wbf_out, DI, mo, mo, DM, DI, DM,
                nullptr, nullptr, nullptr, nullptr);

            // residual + rmsnorm
            rmsnorm_res_k<<<dim3(nt), blk, 0, stream>>>(mo, xin, nw, outp);
        }
    }
}